// Round 2
// baseline (420.887 us; speedup 1.0000x reference)
//
#include <hip/hip_runtime.h>
#include <math.h>

// Problem constants (from reference):
//   N=4096 nodes, K=15 neighbors, D=64 emb dim, IN=5 input feats, H=256 hidden, B=32 batch
#define NN 4096
#define KK 15
#define DD 64
#define HH 256
#define BB 32

__device__ __forceinline__ float wave_reduce_sum(float v) {
  #pragma unroll
  for (int off = 1; off < 64; off <<= 1) v += __shfl_xor(v, off);
  return v;
}

// ---------------------------------------------------------------------------
// Kernel 1: ne = emb / (||emb|| + 1e-8);  e_i = emb @ att[0:64]; e_j = emb @ att[128:192]
// one wave per node
__global__ __launch_bounds__(256) void prep_kernel(
    const float* __restrict__ emb, const float* __restrict__ att,
    float* __restrict__ ne, float* __restrict__ ei, float* __restrict__ ej) {
  int gid = blockIdx.x * 256 + threadIdx.x;
  int n = gid >> 6, lane = gid & 63;
  if (n >= NN) return;
  float v = emb[(size_t)n * DD + lane];
  float s2  = wave_reduce_sum(v * v);
  float sei = wave_reduce_sum(v * att[lane]);
  float sej = wave_reduce_sum(v * att[128 + lane]);
  ne[(size_t)n * DD + lane] = v / (sqrtf(s2) + 1e-8f);
  if (lane == 0) { ei[n] = sei; ej[n] = sej; }
}

// ---------------------------------------------------------------------------
// Kernel 2: sim tile GEMM: sim[r][c] = dot(ne[r], ne[c]), 64x64 tile, K=64 (full)
// LDS tiles stored transposed [d][row] so compute reads are float4.
__global__ __launch_bounds__(256) void sim_kernel(
    const float* __restrict__ ne, float* __restrict__ sim, int row0) {
  __shared__ float As[DD][68];
  __shared__ float Bs[DD][68];
  int t = threadIdx.x;
  int brow = row0 + blockIdx.y * 64;  // global node row of tile
  int bcol = blockIdx.x * 64;

  // load + transpose: thread covers row lr, d-chunk ldc..ldc+15
  int lr = t >> 2, ldc = (t & 3) * 16;
  const float* pa = ne + (size_t)(brow + lr) * DD + ldc;
  const float* pb = ne + (size_t)(bcol + lr) * DD + ldc;
  #pragma unroll
  for (int j = 0; j < 16; j += 4) {
    float4 a = *(const float4*)(pa + j);
    float4 b = *(const float4*)(pb + j);
    float av[4] = {a.x, a.y, a.z, a.w};
    float bv[4] = {b.x, b.y, b.z, b.w};
    #pragma unroll
    for (int q = 0; q < 4; q++) {
      As[ldc + j + q][lr] = av[q];
      Bs[ldc + j + q][lr] = bv[q];
    }
  }
  __syncthreads();

  int tr = t >> 4, tc = t & 15;
  float acc[4][4] = {};
  #pragma unroll 16
  for (int k = 0; k < DD; k++) {
    float4 a = *(const float4*)&As[k][tr * 4];
    float4 b = *(const float4*)&Bs[k][tc * 4];
    float ar[4] = {a.x, a.y, a.z, a.w};
    float br[4] = {b.x, b.y, b.z, b.w};
    #pragma unroll
    for (int i = 0; i < 4; i++)
      #pragma unroll
      for (int j = 0; j < 4; j++)
        acc[i][j] += ar[i] * br[j];
  }

  int lrow = blockIdx.y * 64 + tr * 4;  // buffer-relative row
  #pragma unroll
  for (int i = 0; i < 4; i++) {
    float4 o = {acc[i][0], acc[i][1], acc[i][2], acc[i][3]};
    *(float4*)(sim + (size_t)(lrow + i) * NN + bcol + tc * 4) = o;
  }
}

// ---------------------------------------------------------------------------
// Kernel 3: exact top-15 per row (set semantics; tie -> smaller index via key packing)
__device__ __forceinline__ unsigned long long fkey(float f, int m) {
  unsigned u = __float_as_uint(f);
  unsigned o = (u & 0x80000000u) ? ~u : (u | 0x80000000u);  // order-preserving map
  return ((unsigned long long)o << 32) | (unsigned)(NN - 1 - m);
}

__global__ __launch_bounds__(256) void topk_kernel(
    const float* __restrict__ sim, int* __restrict__ src, int row0) {
  int t = threadIdx.x;
  const float* row = sim + (size_t)blockIdx.x * NN;
  unsigned long long key[16];
  #pragma unroll
  for (int j = 0; j < 16; j++) {
    int m = t + 256 * j;
    key[j] = fkey(row[m], m);
  }
  __shared__ unsigned long long wmax[4];
  __shared__ unsigned long long winner;
  int n = row0 + blockIdx.x;
  int lane = t & 63, wid = t >> 6;
  for (int it = 0; it < KK; it++) {
    unsigned long long loc = key[0];
    #pragma unroll
    for (int j = 1; j < 16; j++) loc = (key[j] > loc) ? key[j] : loc;
    #pragma unroll
    for (int off = 1; off < 64; off <<= 1) {
      unsigned long long o = __shfl_xor(loc, off);
      loc = (o > loc) ? o : loc;
    }
    if (lane == 0) wmax[wid] = loc;
    __syncthreads();
    if (t == 0) {
      unsigned long long w01 = (wmax[0] > wmax[1]) ? wmax[0] : wmax[1];
      unsigned long long w23 = (wmax[2] > wmax[3]) ? wmax[2] : wmax[3];
      winner = (w01 > w23) ? w01 : w23;
    }
    __syncthreads();
    unsigned long long w = winner;
    int m = NN - 1 - (int)(w & 0xffffffffull);
    if (t == (m & 255)) key[m >> 8] = 0ull;  // mark used (0 < any real key)
    if (t == 0) src[n * KK + it] = m;
    __syncthreads();
  }
}

// ---------------------------------------------------------------------------
// Kernel 4: xh[n][b][d] = sum_i x[b][n][i]*lin_w[d][i]; xi = xh@att[64:128]; xj = xh@att[192:256]
// one wave per (n,b) pair, lane = d
__global__ __launch_bounds__(256) void xh_kernel(
    const float* __restrict__ x, const float* __restrict__ lin_w,
    const float* __restrict__ att, float* __restrict__ xh,
    float* __restrict__ xi, float* __restrict__ xj) {
  int gid = blockIdx.x * 256 + threadIdx.x;
  int pair = gid >> 6, lane = gid & 63;
  int n = pair >> 5, b = pair & 31;
  const float* xp = x + ((size_t)b * NN + n) * 5;
  const float* wp = lin_w + lane * 5;
  float v = 0.f;
  #pragma unroll
  for (int i = 0; i < 5; i++) v += xp[i] * wp[i];
  xh[((size_t)n * BB + b) * DD + lane] = v;
  float si = wave_reduce_sum(v * att[64 + lane]);
  float sj = wave_reduce_sum(v * att[192 + lane]);
  if (lane == 0) { xi[pair] = si; xj[pair] = sj; }
}

// ---------------------------------------------------------------------------
// Kernel 5: per node: alpha = softmax_k(leaky_relu(e_i + xi + e_j[src] + xj[src]))
//           gcn[b][d] = sum_k alpha[k][b]*xh[src_k][b][d];  out = gcn * emb[n]
__global__ __launch_bounds__(256) void gcn_kernel(
    const int* __restrict__ src, const float* __restrict__ ei,
    const float* __restrict__ ej, const float* __restrict__ xi,
    const float* __restrict__ xj, const float* __restrict__ xh,
    const float* __restrict__ emb, float* __restrict__ outb) {
  int n = blockIdx.x, t = threadIdx.x;
  __shared__ int s_src[KK];
  __shared__ float s_ej[KK], s_xi[BB], s_alpha[KK][BB], s_emb[DD];
  if (t < KK) { int m = src[n * KK + t]; s_src[t] = m; s_ej[t] = ej[m]; }
  if (t >= 32 && t < 64) s_xi[t - 32] = xi[n * BB + (t - 32)];
  if (t >= 64 && t < 128) s_emb[t - 64] = emb[(size_t)n * DD + (t - 64)];
  __syncthreads();
  // KK*BB = 480 > 256 threads: strided loop (round-0 bug: k>=8 was never computed)
  for (int idx = t; idx < KK * BB; idx += 256) {
    int k = idx >> 5, b = idx & 31;
    float a = ei[n] + s_xi[b] + s_ej[k] + xj[s_src[k] * BB + b];
    a = (a > 0.f) ? a : 0.2f * a;
    s_alpha[k][b] = a;
  }
  __syncthreads();
  if (t < BB) {
    float p[KK];
    float mx = -1e30f;
    #pragma unroll
    for (int k = 0; k < KK; k++) mx = fmaxf(mx, s_alpha[k][t]);
    float s = 0.f;
    #pragma unroll
    for (int k = 0; k < KK; k++) { p[k] = expf(s_alpha[k][t] - mx); s += p[k]; }
    float inv = 1.f / s;
    #pragma unroll
    for (int k = 0; k < KK; k++) s_alpha[k][t] = p[k] * inv;
  }
  __syncthreads();
  int b = t >> 3, d0 = (t & 7) * 8;
  float acc[8] = {};
  for (int k = 0; k < KK; k++) {
    float a = s_alpha[k][b];
    const float* p = xh + ((size_t)s_src[k] * BB + b) * DD + d0;
    float4 u = *(const float4*)p;
    float4 v = *(const float4*)(p + 4);
    acc[0] += a * u.x; acc[1] += a * u.y; acc[2] += a * u.z; acc[3] += a * u.w;
    acc[4] += a * v.x; acc[5] += a * v.y; acc[6] += a * v.z; acc[7] += a * v.w;
  }
  float* op = outb + ((size_t)b * NN + n) * DD + d0;
  #pragma unroll
  for (int j = 0; j < 8; j++) op[j] = acc[j] * s_emb[d0 + j];
}

// ---------------------------------------------------------------------------
// Kernel 6: y[r] = w2 @ relu(out[r] @ w1.T + b1) + b2 for r = b*N+n
// thread t owns hidden unit t: w1 row in 64 VGPRs; activations broadcast from LDS.
__global__ __launch_bounds__(256) void mlp_kernel(
    const float* __restrict__ outb, const float* __restrict__ w1,
    const float* __restrict__ b1, const float* __restrict__ w2,
    const float* __restrict__ b2, float* __restrict__ y) {
  int t = threadIdx.x;
  float wreg[64];
  #pragma unroll
  for (int d = 0; d < DD; d += 4) {
    float4 wv = *(const float4*)(w1 + (size_t)t * DD + d);
    wreg[d] = wv.x; wreg[d + 1] = wv.y; wreg[d + 2] = wv.z; wreg[d + 3] = wv.w;
  }
  float bias = b1[t], w2v = w2[t], b2v = b2[0];
  __shared__ float s_out[16][DD];
  __shared__ float s_part[16][4];
  size_t row0 = (size_t)blockIdx.x * 128;
  int li = t >> 4, ld4 = (t & 15) * 4;
  int lane = t & 63, wid = t >> 6;
  for (int c = 0; c < 128; c += 16) {
    __syncthreads();
    *(float4*)&s_out[li][ld4] = *(const float4*)(outb + (row0 + c + li) * DD + ld4);
    __syncthreads();
    for (int i = 0; i < 16; i++) {
      float hv = bias;
      #pragma unroll
      for (int d = 0; d < DD; d += 4) {
        float4 ov = *(const float4*)&s_out[i][d];
        hv += wreg[d] * ov.x + wreg[d + 1] * ov.y + wreg[d + 2] * ov.z + wreg[d + 3] * ov.w;
      }
      hv = fmaxf(hv, 0.f);
      float p = wave_reduce_sum(hv * w2v);
      if (lane == 0) s_part[i][wid] = p;
    }
    __syncthreads();
    if (t < 16) y[row0 + c + t] = b2v + s_part[t][0] + s_part[t][1] + s_part[t][2] + s_part[t][3];
  }
}

// ---------------------------------------------------------------------------
extern "C" void kernel_launch(void* const* d_in, const int* in_sizes, int n_in,
                              void* d_out, int out_size, void* d_ws, size_t ws_size,
                              hipStream_t stream) {
  const float* x     = (const float*)d_in[0];
  const float* emb   = (const float*)d_in[1];
  const float* lin_w = (const float*)d_in[2];
  const float* att   = (const float*)d_in[3];
  const float* w1    = (const float*)d_in[4];
  const float* b1    = (const float*)d_in[5];
  const float* w2    = (const float*)d_in[6];
  const float* b2    = (const float*)d_in[7];
  float* y = (float*)d_out;

  char* ws = (char*)d_ws;
  // workspace layout (all offsets 256B aligned); peak usage ~66.3 MB
  float* ne     = (float*)(ws + 0);          // N*D          = 1,048,576 B
  float* ei     = (float*)(ws + 1048576);    // N            =    16,384 B
  float* ej     = (float*)(ws + 1064960);    // N            =    16,384 B
  float* xi     = (float*)(ws + 1081344);    // N*B          =   524,288 B
  float* xj     = (float*)(ws + 1605632);    // N*B          =   524,288 B
  int*   srcbuf = (int*)  (ws + 2129920);    // N*K          =   245,760 B
  float* xh     = (float*)(ws + 2375680);    // N*B*D        = 33,554,432 B
  float* simbuf = (float*)(ws + 35930112);   // 2048*N       = 33,554,432 B
  float* outb   = simbuf;                    // overlay: sim consumed before outb written

  prep_kernel<<<NN / 4, 256, 0, stream>>>(emb, att, ne, ei, ej);
  xh_kernel<<<NN * BB / 4, 256, 0, stream>>>(x, lin_w, att, xh, xi, xj);

  for (int half = 0; half < 2; half++) {
    int row0 = half * 2048;
    dim3 g(64, 32);
    sim_kernel<<<g, 256, 0, stream>>>(ne, simbuf, row0);
    topk_kernel<<<2048, 256, 0, stream>>>(simbuf, srcbuf, row0);
  }

  gcn_kernel<<<NN, 256, 0, stream>>>(srcbuf, ei, ej, xi, xj, xh, emb, outb);
  mlp_kernel<<<NN * BB / 128, 256, 0, stream>>>(outb, w1, b1, w2, b2, y);
}

// Round 4
// 257.488 us; speedup vs baseline: 1.6346x; 1.6346x over previous
//
#include <hip/hip_runtime.h>
#include <hip/hip_bf16.h>
#include <math.h>

// Problem constants: N=4096 nodes, K=15 neighbors, D=64, IN=5, H=256 hidden, B=32 batch
#define NN 4096
#define KK 15
#define DD 64
#define HH 256
#define BB 32

typedef __attribute__((ext_vector_type(8))) short s16x8;   // 8 bf16 (MFMA A/B frag)
typedef __attribute__((ext_vector_type(4))) float f32x4;   // MFMA C/D frag

__device__ __forceinline__ float wave_reduce_sum(float v) {
  #pragma unroll
  for (int off = 1; off < 64; off <<= 1) v += __shfl_xor(v, off);
  return v;
}

__device__ __forceinline__ short f2bf(float f) {
  __hip_bfloat16 h = __float2bfloat16(f);
  return *reinterpret_cast<short*>(&h);
}
__device__ __forceinline__ float bf2f(short s) {
  unsigned u = ((unsigned)(unsigned short)s) << 16;
  return __uint_as_float(u);
}

// ---------------------------------------------------------------------------
// Kernel 1: ne = emb / (||emb|| + 1e-8);  e_i = emb @ att[0:64]; e_j = emb @ att[128:192]
__global__ __launch_bounds__(256) void prep_kernel(
    const float* __restrict__ emb, const float* __restrict__ att,
    float* __restrict__ ne, float* __restrict__ ei, float* __restrict__ ej) {
  int gid = blockIdx.x * 256 + threadIdx.x;
  int n = gid >> 6, lane = gid & 63;
  if (n >= NN) return;
  float v = emb[(size_t)n * DD + lane];
  float s2  = wave_reduce_sum(v * v);
  float sei = wave_reduce_sum(v * att[lane]);
  float sej = wave_reduce_sum(v * att[128 + lane]);
  ne[(size_t)n * DD + lane] = v / (sqrtf(s2) + 1e-8f);
  if (lane == 0) { ei[n] = sei; ej[n] = sej; }
}

// ---------------------------------------------------------------------------
// Kernel 1b: w1 -> bf16
__global__ __launch_bounds__(256) void w1cvt_kernel(
    const float* __restrict__ w1, short* __restrict__ w1b) {
  int i = blockIdx.x * 256 + threadIdx.x;
  if (i < HH * DD) w1b[i] = f2bf(w1[i]);
}

// ---------------------------------------------------------------------------
// Kernel 2: sim tile GEMM (fp32 — top-k selection must stay exact-ish)
__global__ __launch_bounds__(256) void sim_kernel(
    const float* __restrict__ ne, float* __restrict__ sim, int row0) {
  __shared__ float As[DD][68];
  __shared__ float Bs[DD][68];
  int t = threadIdx.x;
  int brow = row0 + blockIdx.y * 64;
  int bcol = blockIdx.x * 64;
  int lr = t >> 2, ldc = (t & 3) * 16;
  const float* pa = ne + (size_t)(brow + lr) * DD + ldc;
  const float* pb = ne + (size_t)(bcol + lr) * DD + ldc;
  #pragma unroll
  for (int j = 0; j < 16; j += 4) {
    float4 a = *(const float4*)(pa + j);
    float4 b = *(const float4*)(pb + j);
    float av[4] = {a.x, a.y, a.z, a.w};
    float bv[4] = {b.x, b.y, b.z, b.w};
    #pragma unroll
    for (int q = 0; q < 4; q++) {
      As[ldc + j + q][lr] = av[q];
      Bs[ldc + j + q][lr] = bv[q];
    }
  }
  __syncthreads();
  int tr = t >> 4, tc = t & 15;
  float acc[4][4] = {};
  #pragma unroll 16
  for (int k = 0; k < DD; k++) {
    float4 a = *(const float4*)&As[k][tr * 4];
    float4 b = *(const float4*)&Bs[k][tc * 4];
    float ar[4] = {a.x, a.y, a.z, a.w};
    float br[4] = {b.x, b.y, b.z, b.w};
    #pragma unroll
    for (int i = 0; i < 4; i++)
      #pragma unroll
      for (int j = 0; j < 4; j++)
        acc[i][j] += ar[i] * br[j];
  }
  int lrow = blockIdx.y * 64 + tr * 4;
  #pragma unroll
  for (int i = 0; i < 4; i++) {
    float4 o = {acc[i][0], acc[i][1], acc[i][2], acc[i][3]};
    *(float4*)(sim + (size_t)(lrow + i) * NN + bcol + tc * 4) = o;
  }
}

// ---------------------------------------------------------------------------
// Kernel 3: exact top-15 per row
__device__ __forceinline__ unsigned long long fkey(float f, int m) {
  unsigned u = __float_as_uint(f);
  unsigned o = (u & 0x80000000u) ? ~u : (u | 0x80000000u);
  return ((unsigned long long)o << 32) | (unsigned)(NN - 1 - m);
}

__global__ __launch_bounds__(256) void topk_kernel(
    const float* __restrict__ sim, int* __restrict__ src, int row0) {
  int t = threadIdx.x;
  const float* row = sim + (size_t)blockIdx.x * NN;
  unsigned long long key[16];
  #pragma unroll
  for (int j = 0; j < 16; j++) {
    int m = t + 256 * j;
    key[j] = fkey(row[m], m);
  }
  __shared__ unsigned long long wmax[4];
  __shared__ unsigned long long winner;
  int n = row0 + blockIdx.x;
  int lane = t & 63, wid = t >> 6;
  for (int it = 0; it < KK; it++) {
    unsigned long long loc = key[0];
    #pragma unroll
    for (int j = 1; j < 16; j++) loc = (key[j] > loc) ? key[j] : loc;
    #pragma unroll
    for (int off = 1; off < 64; off <<= 1) {
      unsigned long long o = __shfl_xor(loc, off);
      loc = (o > loc) ? o : loc;
    }
    if (lane == 0) wmax[wid] = loc;
    __syncthreads();
    if (t == 0) {
      unsigned long long w01 = (wmax[0] > wmax[1]) ? wmax[0] : wmax[1];
      unsigned long long w23 = (wmax[2] > wmax[3]) ? wmax[2] : wmax[3];
      winner = (w01 > w23) ? w01 : w23;
    }
    __syncthreads();
    unsigned long long w = winner;
    int m = NN - 1 - (int)(w & 0xffffffffull);
    if (t == (m & 255)) key[m >> 8] = 0ull;
    if (t == 0) src[n * KK + it] = m;
    __syncthreads();
  }
}

// ---------------------------------------------------------------------------
// Kernel 4: xh (bf16 store) + xi/xj (fp32)
__global__ __launch_bounds__(256) void xh_kernel(
    const float* __restrict__ x, const float* __restrict__ lin_w,
    const float* __restrict__ att, short* __restrict__ xh,
    float* __restrict__ xi, float* __restrict__ xj) {
  int gid = blockIdx.x * 256 + threadIdx.x;
  int pair = gid >> 6, lane = gid & 63;
  int n = pair >> 5, b = pair & 31;
  const float* xp = x + ((size_t)b * NN + n) * 5;
  const float* wp = lin_w + lane * 5;
  float v = 0.f;
  #pragma unroll
  for (int i = 0; i < 5; i++) v += xp[i] * wp[i];
  xh[((size_t)n * BB + b) * DD + lane] = f2bf(v);
  float si = wave_reduce_sum(v * att[64 + lane]);
  float sj = wave_reduce_sum(v * att[192 + lane]);
  if (lane == 0) { xi[pair] = si; xj[pair] = sj; }
}

// ---------------------------------------------------------------------------
// Kernel 5: alpha softmax + gathered weighted sum; out = gcn * emb  (bf16 store)
__global__ __launch_bounds__(256) void gcn_kernel(
    const int* __restrict__ src, const float* __restrict__ ei,
    const float* __restrict__ ej, const float* __restrict__ xi,
    const float* __restrict__ xj, const short* __restrict__ xh,
    const float* __restrict__ emb, short* __restrict__ outb) {
  int n = blockIdx.x, t = threadIdx.x;
  __shared__ int s_src[KK];
  __shared__ float s_ej[KK], s_xi[BB], s_alpha[KK][BB], s_emb[DD];
  if (t < KK) { int m = src[n * KK + t]; s_src[t] = m; s_ej[t] = ej[m]; }
  if (t >= 32 && t < 64) s_xi[t - 32] = xi[n * BB + (t - 32)];
  if (t >= 64 && t < 128) s_emb[t - 64] = emb[(size_t)n * DD + (t - 64)];
  __syncthreads();
  for (int idx = t; idx < KK * BB; idx += 256) {
    int k = idx >> 5, b = idx & 31;
    float a = ei[n] + s_xi[b] + s_ej[k] + xj[s_src[k] * BB + b];
    a = (a > 0.f) ? a : 0.2f * a;
    s_alpha[k][b] = a;
  }
  __syncthreads();
  if (t < BB) {
    float p[KK];
    float mx = -1e30f;
    #pragma unroll
    for (int k = 0; k < KK; k++) mx = fmaxf(mx, s_alpha[k][t]);
    float s = 0.f;
    #pragma unroll
    for (int k = 0; k < KK; k++) { p[k] = expf(s_alpha[k][t] - mx); s += p[k]; }
    float inv = 1.f / s;
    #pragma unroll
    for (int k = 0; k < KK; k++) s_alpha[k][t] = p[k] * inv;
  }
  __syncthreads();
  int b = t >> 3, d0 = (t & 7) * 8;
  float acc[8] = {};
  for (int k = 0; k < KK; k++) {
    float a = s_alpha[k][b];
    const short* p = xh + ((size_t)s_src[k] * BB + b) * DD + d0;
    s16x8 u = *(const s16x8*)p;
    #pragma unroll
    for (int j = 0; j < 8; j++) acc[j] += a * bf2f(u[j]);
  }
  short* op = outb + ((size_t)b * NN + n) * DD + d0;
  s16x8 o;
  #pragma unroll
  for (int j = 0; j < 8; j++) o[j] = f2bf(acc[j] * s_emb[d0 + j]);
  *(s16x8*)op = o;
}

// ---------------------------------------------------------------------------
// Kernel 6: MFMA MLP.  rows r = b*N+n (131072), y[r] = w2 @ relu(out[r]@w1^T + b1) + b2
// Block = 4 waves; wave w owns hidden cols 64w..64w+63 (w1 frags in regs, reused
// over 4 row-chunks of 64). A-frags (bf16 out rows) loaded straight from global.
// mfma_f32_16x16x32_bf16: A lane l -> row=l&15, k=(l>>4)*8+e ; C: col=l&15, row=(l>>4)*4+reg.
__global__ __launch_bounds__(256) void mlp_mfma_kernel(
    const short* __restrict__ outb, const short* __restrict__ w1b,
    const float* __restrict__ b1, const float* __restrict__ w2,
    const float* __restrict__ b2, float* __restrict__ y) {
  int t = threadIdx.x;
  int w = t >> 6, l = t & 63;
  int lm = l & 15, lk = l >> 4;

  s16x8 bfrag[4][2];
  float b1v[4], w2v[4];
  #pragma unroll
  for (int j = 0; j < 4; j++) {
    int c = 64 * w + 16 * j + lm;
    #pragma unroll
    for (int s = 0; s < 2; s++)
      bfrag[j][s] = *(const s16x8*)(w1b + (size_t)c * DD + s * 32 + lk * 8);
    b1v[j] = b1[c];
    w2v[j] = w2[c];
  }
  float b2v = b2[0];
  __shared__ float part[4][64];
  size_t row_base = (size_t)blockIdx.x * 256;

  for (int chunk = 0; chunk < 4; chunk++) {
    size_t r0 = row_base + chunk * 64;
    f32x4 acc[4][4] = {};
    #pragma unroll
    for (int s = 0; s < 2; s++) {
      s16x8 afrag[4];
      #pragma unroll
      for (int i = 0; i < 4; i++) {
        size_t row = r0 + 16 * i + lm;
        afrag[i] = *(const s16x8*)(outb + row * DD + s * 32 + lk * 8);
      }
      #pragma unroll
      for (int i = 0; i < 4; i++)
        #pragma unroll
        for (int j = 0; j < 4; j++)
          acc[i][j] = __builtin_amdgcn_mfma_f32_16x16x32_bf16(
              afrag[i], bfrag[j][s], acc[i][j], 0, 0, 0);
    }
    // epilogue: relu + w2-weighted col sum (4 cols in-lane), 16-lane shfl reduce
    float p[4][4];
    #pragma unroll
    for (int i = 0; i < 4; i++)
      #pragma unroll
      for (int r = 0; r < 4; r++) {
        float sum = 0.f;
        #pragma unroll
        for (int j = 0; j < 4; j++) {
          float h = acc[i][j][r] + b1v[j];
          h = fmaxf(h, 0.f);
          sum += h * w2v[j];
        }
        p[i][r] = sum;
      }
    #pragma unroll
    for (int off = 1; off < 16; off <<= 1)
      #pragma unroll
      for (int i = 0; i < 4; i++)
        #pragma unroll
        for (int r = 0; r < 4; r++)
          p[i][r] += __shfl_xor(p[i][r], off);
    if (lm == 0) {
      #pragma unroll
      for (int i = 0; i < 4; i++)
        #pragma unroll
        for (int r = 0; r < 4; r++)
          part[w][16 * i + 4 * lk + r] = p[i][r];
    }
    __syncthreads();
    if (t < 64)
      y[r0 + t] = b2v + part[0][t] + part[1][t] + part[2][t] + part[3][t];
    __syncthreads();
  }
}

// ---------------------------------------------------------------------------
extern "C" void kernel_launch(void* const* d_in, const int* in_sizes, int n_in,
                              void* d_out, int out_size, void* d_ws, size_t ws_size,
                              hipStream_t stream) {
  const float* x     = (const float*)d_in[0];
  const float* emb   = (const float*)d_in[1];
  const float* lin_w = (const float*)d_in[2];
  const float* att   = (const float*)d_in[3];
  const float* w1    = (const float*)d_in[4];
  const float* b1    = (const float*)d_in[5];
  const float* w2    = (const float*)d_in[6];
  const float* b2    = (const float*)d_in[7];
  float* y = (float*)d_out;

  char* ws = (char*)d_ws;
  // workspace layout (256B aligned), peak ~53 MB
  float* ne     = (float*)(ws + 0);          // N*D f32      = 1,048,576 B
  float* ei     = (float*)(ws + 1048576);    // N f32        =    16,384 B
  float* ej     = (float*)(ws + 1064960);    // N f32        =    16,384 B
  float* xi     = (float*)(ws + 1081344);    // N*B f32      =   524,288 B
  float* xj     = (float*)(ws + 1605632);    // N*B f32      =   524,288 B
  int*   srcbuf = (int*)  (ws + 2129920);    // N*K i32      =   245,760 B
  short* w1b    = (short*)(ws + 2375680);    // H*D bf16     =    32,768 B
  short* xh     = (short*)(ws + 2408448);    // N*B*D bf16   = 16,777,216 B
  float* simbuf = (float*)(ws + 19185664);   // 2048*N f32   = 33,554,432 B
  short* outb   = (short*)simbuf;            // overlay: sim fully consumed before outb written

  prep_kernel<<<NN / 4, 256, 0, stream>>>(emb, att, ne, ei, ej);
  w1cvt_kernel<<<(HH * DD) / 256, 256, 0, stream>>>(w1, w1b);
  xh_kernel<<<NN * BB / 4, 256, 0, stream>>>(x, lin_w, att, xh, xi, xj);

  for (int half = 0; half < 2; half++) {
    int row0 = half * 2048;
    dim3 g(64, 32);
    sim_kernel<<<g, 256, 0, stream>>>(ne, simbuf, row0);
    topk_kernel<<<2048, 256, 0, stream>>>(simbuf, srcbuf, row0);
  }

  gcn_kernel<<<NN, 256, 0, stream>>>(srcbuf, ei, ej, xi, xj, xh, emb, outb);
  mlp_mfma_kernel<<<NN * BB / 256, 256, 0, stream>>>(outb, w1b, b1, w2, b2, y);
}

// Round 6
// 242.570 us; speedup vs baseline: 1.7351x; 1.0615x over previous
//
#include <hip/hip_runtime.h>
#include <hip/hip_bf16.h>
#include <math.h>

// Problem constants: N=4096 nodes, K=15 neighbors, D=64, IN=5, H=256 hidden, B=32 batch
#define NN 4096
#define KK 15
#define DD 64
#define HH 256
#define BB 32

typedef __attribute__((ext_vector_type(8))) short s16x8;   // 8 bf16 (MFMA A/B frag)
typedef __attribute__((ext_vector_type(4))) float f32x4;   // MFMA C/D frag

__device__ __forceinline__ float wave_reduce_sum(float v) {
  #pragma unroll
  for (int off = 1; off < 64; off <<= 1) v += __shfl_xor(v, off);
  return v;
}

__device__ __forceinline__ short f2bf(float f) {
  __hip_bfloat16 h = __float2bfloat16(f);
  return *reinterpret_cast<short*>(&h);
}
__device__ __forceinline__ float bf2f(short s) {
  unsigned u = ((unsigned)(unsigned short)s) << 16;
  return __uint_as_float(u);
}

// ---------------------------------------------------------------------------
// Kernel 1: ne = emb / (||emb|| + 1e-8);  e_i = emb @ att[0:64]; e_j = emb @ att[128:192]
__global__ __launch_bounds__(256) void prep_kernel(
    const float* __restrict__ emb, const float* __restrict__ att,
    float* __restrict__ ne, float* __restrict__ ei, float* __restrict__ ej) {
  int gid = blockIdx.x * 256 + threadIdx.x;
  int n = gid >> 6, lane = gid & 63;
  if (n >= NN) return;
  float v = emb[(size_t)n * DD + lane];
  float s2  = wave_reduce_sum(v * v);
  float sei = wave_reduce_sum(v * att[lane]);
  float sej = wave_reduce_sum(v * att[128 + lane]);
  ne[(size_t)n * DD + lane] = v / (sqrtf(s2) + 1e-8f);
  if (lane == 0) { ei[n] = sei; ej[n] = sej; }
}

// ---------------------------------------------------------------------------
// Kernel 1b: w1 -> bf16
__global__ __launch_bounds__(256) void w1cvt_kernel(
    const float* __restrict__ w1, short* __restrict__ w1b) {
  int i = blockIdx.x * 256 + threadIdx.x;
  if (i < HH * DD) w1b[i] = f2bf(w1[i]);
}

// ---------------------------------------------------------------------------
// Kernel 2: sim tile GEMM (fp32 — top-k selection must stay exact)
__global__ __launch_bounds__(256) void sim_kernel(
    const float* __restrict__ ne, float* __restrict__ sim) {
  __shared__ float As[DD][68];
  __shared__ float Bs[DD][68];
  int t = threadIdx.x;
  int brow = blockIdx.y * 64;
  int bcol = blockIdx.x * 64;
  int lr = t >> 2, ldc = (t & 3) * 16;
  const float* pa = ne + (size_t)(brow + lr) * DD + ldc;
  const float* pb = ne + (size_t)(bcol + lr) * DD + ldc;
  #pragma unroll
  for (int j = 0; j < 16; j += 4) {
    float4 a = *(const float4*)(pa + j);
    float4 b = *(const float4*)(pb + j);
    float av[4] = {a.x, a.y, a.z, a.w};
    float bv[4] = {b.x, b.y, b.z, b.w};
    #pragma unroll
    for (int q = 0; q < 4; q++) {
      As[ldc + j + q][lr] = av[q];
      Bs[ldc + j + q][lr] = bv[q];
    }
  }
  __syncthreads();
  int tr = t >> 4, tc = t & 15;
  float acc[4][4] = {};
  #pragma unroll 16
  for (int k = 0; k < DD; k++) {
    float4 a = *(const float4*)&As[k][tr * 4];
    float4 b = *(const float4*)&Bs[k][tc * 4];
    float ar[4] = {a.x, a.y, a.z, a.w};
    float br[4] = {b.x, b.y, b.z, b.w};
    #pragma unroll
    for (int i = 0; i < 4; i++)
      #pragma unroll
      for (int j = 0; j < 4; j++)
        acc[i][j] += ar[i] * br[j];
  }
  int grow = brow + tr * 4;
  #pragma unroll
  for (int i = 0; i < 4; i++) {
    float4 o = {acc[i][0], acc[i][1], acc[i][2], acc[i][3]};
    *(float4*)(sim + (size_t)(grow + i) * NN + bcol + tc * 4) = o;
  }
}

// ---------------------------------------------------------------------------
// Kernel 3: exact top-15 per row — hierarchical wave selection, 1 barrier total.
// Wave w owns cols [1024w,1024w+1024): 16 keys/lane; 15 shuffle-argmax rounds with
// cached lane-local max (only knocked-out lane recomputes). Then wave 0 merges 60 cands.
__device__ __forceinline__ unsigned long long fkey(float f, int m) {
  unsigned u = __float_as_uint(f);
  unsigned o = (u & 0x80000000u) ? ~u : (u | 0x80000000u);  // order-preserving
  return ((unsigned long long)o << 32) | (unsigned)(NN - 1 - m);
}

__global__ __launch_bounds__(256) void topk_kernel(
    const float* __restrict__ sim, int* __restrict__ src) {
  int t = threadIdx.x;
  int w = t >> 6, l = t & 63;
  int n = blockIdx.x;
  const float* row = sim + (size_t)n * NN;
  unsigned long long key[16];
  int base = w * 1024;
  #pragma unroll
  for (int c = 0; c < 4; c++) {
    int col = base + c * 256 + l * 4;
    float4 v = *(const float4*)(row + col);
    key[c * 4 + 0] = fkey(v.x, col + 0);
    key[c * 4 + 1] = fkey(v.y, col + 1);
    key[c * 4 + 2] = fkey(v.z, col + 2);
    key[c * 4 + 3] = fkey(v.w, col + 3);
  }
  unsigned long long lm = key[0];
  #pragma unroll
  for (int j = 1; j < 16; j++) lm = (key[j] > lm) ? key[j] : lm;

  __shared__ unsigned long long cand[4 * KK];
  for (int it = 0; it < KK; it++) {
    unsigned long long wm = lm;
    #pragma unroll
    for (int off = 1; off < 64; off <<= 1) {
      unsigned long long o = __shfl_xor(wm, off);
      wm = (o > wm) ? o : wm;
    }
    if (lm == wm) {  // exactly one lane (keys unique): knockout + recompute local max
      #pragma unroll
      for (int j = 0; j < 16; j++) if (key[j] == wm) key[j] = 0ull;
      lm = key[0];
      #pragma unroll
      for (int j = 1; j < 16; j++) lm = (key[j] > lm) ? key[j] : lm;
    }
    if (l == 0) cand[w * KK + it] = wm;
  }
  __syncthreads();
  if (w == 0) {
    unsigned long long k2 = (l < 4 * KK) ? cand[l] : 0ull;
    for (int it = 0; it < KK; it++) {
      unsigned long long wm = k2;
      #pragma unroll
      for (int off = 1; off < 64; off <<= 1) {
        unsigned long long o = __shfl_xor(wm, off);
        wm = (o > wm) ? o : wm;
      }
      if (k2 == wm) k2 = 0ull;
      if (l == 0) src[n * KK + it] = NN - 1 - (int)(wm & 0xffffffffull);
    }
  }
}

// ---------------------------------------------------------------------------
// Kernel 4: xh (bf16 store) + xi/xj (fp32)
__global__ __launch_bounds__(256) void xh_kernel(
    const float* __restrict__ x, const float* __restrict__ lin_w,
    const float* __restrict__ att, short* __restrict__ xh,
    float* __restrict__ xi, float* __restrict__ xj) {
  int gid = blockIdx.x * 256 + threadIdx.x;
  int pair = gid >> 6, lane = gid & 63;
  int n = pair >> 5, b = pair & 31;
  const float* xp = x + ((size_t)b * NN + n) * 5;
  const float* wp = lin_w + lane * 5;
  float v = 0.f;
  #pragma unroll
  for (int i = 0; i < 5; i++) v += xp[i] * wp[i];
  xh[((size_t)n * BB + b) * DD + lane] = f2bf(v);
  float si = wave_reduce_sum(v * att[64 + lane]);
  float sj = wave_reduce_sum(v * att[192 + lane]);
  if (lane == 0) { xi[pair] = si; xj[pair] = sj; }
}

// ---------------------------------------------------------------------------
// Kernel 5: alpha softmax + gathered weighted sum; out = gcn * emb  (bf16 store)
__global__ __launch_bounds__(256) void gcn_kernel(
    const int* __restrict__ src, const float* __restrict__ ei,
    const float* __restrict__ ej, const float* __restrict__ xi,
    const float* __restrict__ xj, const short* __restrict__ xh,
    const float* __restrict__ emb, short* __restrict__ outb) {
  int n = blockIdx.x, t = threadIdx.x;
  __shared__ int s_src[KK];
  __shared__ float s_ej[KK], s_xi[BB], s_alpha[KK][BB], s_emb[DD];
  if (t < KK) { int m = src[n * KK + t]; s_src[t] = m; s_ej[t] = ej[m]; }
  if (t >= 32 && t < 64) s_xi[t - 32] = xi[n * BB + (t - 32)];
  if (t >= 64 && t < 128) s_emb[t - 64] = emb[(size_t)n * DD + (t - 64)];
  __syncthreads();
  for (int idx = t; idx < KK * BB; idx += 256) {
    int k = idx >> 5, b = idx & 31;
    float a = ei[n] + s_xi[b] + s_ej[k] + xj[s_src[k] * BB + b];
    a = (a > 0.f) ? a : 0.2f * a;
    s_alpha[k][b] = a;
  }
  __syncthreads();
  if (t < BB) {
    float p[KK];
    float mx = -1e30f;
    #pragma unroll
    for (int k = 0; k < KK; k++) mx = fmaxf(mx, s_alpha[k][t]);
    float s = 0.f;
    #pragma unroll
    for (int k = 0; k < KK; k++) { p[k] = expf(s_alpha[k][t] - mx); s += p[k]; }
    float inv = 1.f / s;
    #pragma unroll
    for (int k = 0; k < KK; k++) s_alpha[k][t] = p[k] * inv;
  }
  __syncthreads();
  int b = t >> 3, d0 = (t & 7) * 8;
  float acc[8] = {};
  for (int k = 0; k < KK; k++) {
    float a = s_alpha[k][b];
    const short* p = xh + ((size_t)s_src[k] * BB + b) * DD + d0;
    s16x8 u = *(const s16x8*)p;
    #pragma unroll
    for (int j = 0; j < 8; j++) acc[j] += a * bf2f(u[j]);
  }
  short* op = outb + ((size_t)b * NN + n) * DD + d0;
  s16x8 o;
  #pragma unroll
  for (int j = 0; j < 8; j++) o[j] = f2bf(acc[j] * s_emb[d0 + j]);
  *(s16x8*)op = o;
}

// ---------------------------------------------------------------------------
// Kernel 6: MFMA MLP.  rows r = b*N+n (131072), y[r] = w2 @ relu(out[r]@w1^T + b1) + b2
__global__ __launch_bounds__(256) void mlp_mfma_kernel(
    const short* __restrict__ outb, const short* __restrict__ w1b,
    const float* __restrict__ b1, const float* __restrict__ w2,
    const float* __restrict__ b2, float* __restrict__ y) {
  int t = threadIdx.x;
  int w = t >> 6, l = t & 63;
  int lm = l & 15, lk = l >> 4;

  s16x8 bfrag[4][2];
  float b1v[4], w2v[4];
  #pragma unroll
  for (int j = 0; j < 4; j++) {
    int c = 64 * w + 16 * j + lm;
    #pragma unroll
    for (int s = 0; s < 2; s++)
      bfrag[j][s] = *(const s16x8*)(w1b + (size_t)c * DD + s * 32 + lk * 8);
    b1v[j] = b1[c];
    w2v[j] = w2[c];
  }
  float b2v = b2[0];
  __shared__ float part[4][64];
  size_t row_base = (size_t)blockIdx.x * 256;

  for (int chunk = 0; chunk < 4; chunk++) {
    size_t r0 = row_base + chunk * 64;
    f32x4 acc[4][4] = {};
    #pragma unroll
    for (int s = 0; s < 2; s++) {
      s16x8 afrag[4];
      #pragma unroll
      for (int i = 0; i < 4; i++) {
        size_t row = r0 + 16 * i + lm;
        afrag[i] = *(const s16x8*)(outb + row * DD + s * 32 + lk * 8);
      }
      #pragma unroll
      for (int i = 0; i < 4; i++)
        #pragma unroll
        for (int j = 0; j < 4; j++)
          acc[i][j] = __builtin_amdgcn_mfma_f32_16x16x32_bf16(
              afrag[i], bfrag[j][s], acc[i][j], 0, 0, 0);
    }
    float p[4][4];
    #pragma unroll
    for (int i = 0; i < 4; i++)
      #pragma unroll
      for (int r = 0; r < 4; r++) {
        float sum = 0.f;
        #pragma unroll
        for (int j = 0; j < 4; j++) {
          float h = acc[i][j][r] + b1v[j];
          h = fmaxf(h, 0.f);
          sum += h * w2v[j];
        }
        p[i][r] = sum;
      }
    #pragma unroll
    for (int off = 1; off < 16; off <<= 1)
      #pragma unroll
      for (int i = 0; i < 4; i++)
        #pragma unroll
        for (int r = 0; r < 4; r++)
          p[i][r] += __shfl_xor(p[i][r], off);
    if (lm == 0) {
      #pragma unroll
      for (int i = 0; i < 4; i++)
        #pragma unroll
        for (int r = 0; r < 4; r++)
          part[w][16 * i + 4 * lk + r] = p[i][r];
    }
    __syncthreads();
    if (t < 64)
      y[r0 + t] = b2v + part[0][t] + part[1][t] + part[2][t] + part[3][t];
    __syncthreads();
  }
}

// ---------------------------------------------------------------------------
extern "C" void kernel_launch(void* const* d_in, const int* in_sizes, int n_in,
                              void* d_out, int out_size, void* d_ws, size_t ws_size,
                              hipStream_t stream) {
  const float* x     = (const float*)d_in[0];
  const float* emb   = (const float*)d_in[1];
  const float* lin_w = (const float*)d_in[2];
  const float* att   = (const float*)d_in[3];
  const float* w1    = (const float*)d_in[4];
  const float* b1    = (const float*)d_in[5];
  const float* w2    = (const float*)d_in[6];
  const float* b2    = (const float*)d_in[7];
  float* y = (float*)d_out;

  char* ws = (char*)d_ws;
  // workspace layout (256B aligned), peak ~86.3 MB (ws is 256 MiB per harness poison)
  float* ne     = (float*)(ws + 0);          // N*D f32      = 1,048,576 B
  float* ei     = (float*)(ws + 1048576);    // N f32        =    16,384 B
  float* ej     = (float*)(ws + 1064960);    // N f32        =    16,384 B
  float* xi     = (float*)(ws + 1081344);    // N*B f32      =   524,288 B
  float* xj     = (float*)(ws + 1605632);    // N*B f32      =   524,288 B
  int*   srcbuf = (int*)  (ws + 2129920);    // N*K i32      =   245,760 B
  short* w1b    = (short*)(ws + 2375680);    // H*D bf16     =    32,768 B
  short* xh     = (short*)(ws + 2408448);    // N*B*D bf16   = 16,777,216 B
  float* simbuf = (float*)(ws + 19185664);   // N*N f32      = 67,108,864 B
  short* outb   = (short*)simbuf;            // overlay: sim fully consumed before outb written

  prep_kernel<<<NN / 4, 256, 0, stream>>>(emb, att, ne, ei, ej);
  w1cvt_kernel<<<(HH * DD) / 256, 256, 0, stream>>>(w1, w1b);
  xh_kernel<<<NN * BB / 4, 256, 0, stream>>>(x, lin_w, att, xh, xi, xj);

  dim3 g(64, 64);
  sim_kernel<<<g, 256, 0, stream>>>(ne, simbuf);
  topk_kernel<<<NN, 256, 0, stream>>>(simbuf, srcbuf);

  gcn_kernel<<<NN, 256, 0, stream>>>(srcbuf, ei, ej, xi, xj, xh, emb, outb);
  mlp_mfma_kernel<<<NN * BB / 256, 256, 0, stream>>>(outb, w1b, b1, w2, b2, y);
}

// Round 8
// 230.610 us; speedup vs baseline: 1.8251x; 1.0519x over previous
//
#include <hip/hip_runtime.h>
#include <hip/hip_bf16.h>
#include <math.h>

// Problem constants: N=4096 nodes, K=15 neighbors, D=64, IN=5, H=256 hidden, B=32 batch
#define NN 4096
#define KK 15
#define DD 64
#define HH 256
#define BB 32

typedef __attribute__((ext_vector_type(8))) short s16x8;   // 8 bf16 (MFMA A/B frag)
typedef __attribute__((ext_vector_type(4))) float f32x4;   // MFMA C/D frag

__device__ __forceinline__ float wave_reduce_sum(float v) {
  #pragma unroll
  for (int off = 1; off < 64; off <<= 1) v += __shfl_xor(v, off);
  return v;
}

__device__ __forceinline__ short f2bf(float f) {
  __hip_bfloat16 h = __float2bfloat16(f);
  return *reinterpret_cast<short*>(&h);
}
__device__ __forceinline__ float bf2f(short s) {
  unsigned u = ((unsigned)(unsigned short)s) << 16;
  return __uint_as_float(u);
}

// ---------------------------------------------------------------------------
// Kernel 1: ne = emb / (||emb|| + 1e-8);  e_i = emb @ att[0:64]; e_j = emb @ att[128:192]
__global__ __launch_bounds__(256) void prep_kernel(
    const float* __restrict__ emb, const float* __restrict__ att,
    float* __restrict__ ne, float* __restrict__ ei, float* __restrict__ ej) {
  int gid = blockIdx.x * 256 + threadIdx.x;
  int n = gid >> 6, lane = gid & 63;
  if (n >= NN) return;
  float v = emb[(size_t)n * DD + lane];
  float s2  = wave_reduce_sum(v * v);
  float sei = wave_reduce_sum(v * att[lane]);
  float sej = wave_reduce_sum(v * att[128 + lane]);
  ne[(size_t)n * DD + lane] = v / (sqrtf(s2) + 1e-8f);
  if (lane == 0) { ei[n] = sei; ej[n] = sej; }
}

// ---------------------------------------------------------------------------
// Kernel 1b: w1 -> bf16
__global__ __launch_bounds__(256) void w1cvt_kernel(
    const float* __restrict__ w1, short* __restrict__ w1b) {
  int i = blockIdx.x * 256 + threadIdx.x;
  if (i < HH * DD) w1b[i] = f2bf(w1[i]);
}

// ---------------------------------------------------------------------------
// Kernel 2: sim tile GEMM (fp32 — top-k selection must stay exact)
__global__ __launch_bounds__(256) void sim_kernel(
    const float* __restrict__ ne, float* __restrict__ sim) {
  __shared__ float As[DD][68];
  __shared__ float Bs[DD][68];
  int t = threadIdx.x;
  int brow = blockIdx.y * 64;
  int bcol = blockIdx.x * 64;
  int lr = t >> 2, ldc = (t & 3) * 16;
  const float* pa = ne + (size_t)(brow + lr) * DD + ldc;
  const float* pb = ne + (size_t)(bcol + lr) * DD + ldc;
  #pragma unroll
  for (int j = 0; j < 16; j += 4) {
    float4 a = *(const float4*)(pa + j);
    float4 b = *(const float4*)(pb + j);
    float av[4] = {a.x, a.y, a.z, a.w};
    float bv[4] = {b.x, b.y, b.z, b.w};
    #pragma unroll
    for (int q = 0; q < 4; q++) {
      As[ldc + j + q][lr] = av[q];
      Bs[ldc + j + q][lr] = bv[q];
    }
  }
  __syncthreads();
  int tr = t >> 4, tc = t & 15;
  float acc[4][4] = {};
  #pragma unroll 16
  for (int k = 0; k < DD; k++) {
    float4 a = *(const float4*)&As[k][tr * 4];
    float4 b = *(const float4*)&Bs[k][tc * 4];
    float ar[4] = {a.x, a.y, a.z, a.w};
    float br[4] = {b.x, b.y, b.z, b.w};
    #pragma unroll
    for (int i = 0; i < 4; i++)
      #pragma unroll
      for (int j = 0; j < 4; j++)
        acc[i][j] += ar[i] * br[j];
  }
  int grow = brow + tr * 4;
  #pragma unroll
  for (int i = 0; i < 4; i++) {
    float4 o = {acc[i][0], acc[i][1], acc[i][2], acc[i][3]};
    *(float4*)(sim + (size_t)(grow + i) * NN + bcol + tc * 4) = o;
  }
}

// ---------------------------------------------------------------------------
// Kernel 3: exact top-15 per row.
// Stage 1: 16 groups of 16 lanes; group g owns cols [256g, 256g+256), 16/lane in
// registers. 15 rounds of DPP 16-lane float argmax (pure VALU pipe, 16 groups in
// SIMT lockstep). Owner lane knocks out by value and emits (o32|revcol) to LDS.
// Stage 2: rank pass over 240 unique u64 candidates; rank<15 -> src[n*15+rank].
#define DPPMAX(x, CTRL)                                                     \
  x = fmaxf(x, __int_as_float(__builtin_amdgcn_update_dpp(                  \
          __float_as_int(x), __float_as_int(x), (CTRL), 0xF, 0xF, true)))

__global__ __launch_bounds__(256) void topk_kernel(
    const float* __restrict__ sim, int* __restrict__ src) {
  int t = threadIdx.x;
  int g = t >> 4, gi = t & 15;
  int n = blockIdx.x;
  const float* rp = sim + (size_t)n * NN + g * 256 + gi * 16;
  float v[16];
  #pragma unroll
  for (int c = 0; c < 4; c++) {
    float4 f = *(const float4*)(rp + c * 4);
    v[c * 4 + 0] = f.x; v[c * 4 + 1] = f.y; v[c * 4 + 2] = f.z; v[c * 4 + 3] = f.w;
  }
  float lm = v[0];
  #pragma unroll
  for (int j = 1; j < 16; j++) lm = fmaxf(lm, v[j]);

  __shared__ unsigned long long cand[16 * KK];
  #pragma unroll 1
  for (int it = 0; it < KK; it++) {
    float gm = lm;
    DPPMAX(gm, 0xB1);   // quad_perm(1,0,3,2): xor1
    DPPMAX(gm, 0x4E);   // quad_perm(2,3,0,1): xor2
    DPPMAX(gm, 0x141);  // row_half_mirror: xor7 -> max of 8
    DPPMAX(gm, 0x140);  // row_mirror: xor15 -> max of 16
    if (lm == gm) {     // owner lane (float-equality ties: measure-zero)
      int j = 0;
      #pragma unroll
      for (int q = 15; q >= 0; q--) if (v[q] == gm) j = q;  // smallest col on tie
      #pragma unroll
      for (int q = 0; q < 16; q++) if (v[q] == gm) v[q] = -3e38f;
      lm = v[0];
      #pragma unroll
      for (int q = 1; q < 16; q++) lm = fmaxf(lm, v[q]);
      unsigned u = __float_as_uint(gm);
      unsigned o = (u & 0x80000000u) ? ~u : (u | 0x80000000u);
      int col = g * 256 + gi * 16 + j;
      cand[g * KK + it] = ((unsigned long long)o << 32) | (unsigned)(NN - 1 - col);
    }
  }
  __syncthreads();
  // Stage 2: exact rank of each candidate among all 240 (keys unique).
  unsigned long long mykey = (t < 16 * KK) ? cand[t] : 0ull;
  int rank = 0;
  #pragma unroll 4
  for (int i = 0; i < 16 * KK; i++) rank += (cand[i] > mykey) ? 1 : 0;
  if (t < 16 * KK && rank < KK)
    src[n * KK + rank] = NN - 1 - (int)(mykey & 0xffffffffull);
}

// ---------------------------------------------------------------------------
// Kernel 4: xh (bf16 store) + xi/xj (fp32)
__global__ __launch_bounds__(256) void xh_kernel(
    const float* __restrict__ x, const float* __restrict__ lin_w,
    const float* __restrict__ att, short* __restrict__ xh,
    float* __restrict__ xi, float* __restrict__ xj) {
  int gid = blockIdx.x * 256 + threadIdx.x;
  int pair = gid >> 6, lane = gid & 63;
  int n = pair >> 5, b = pair & 31;
  const float* xp = x + ((size_t)b * NN + n) * 5;
  const float* wp = lin_w + lane * 5;
  float v = 0.f;
  #pragma unroll
  for (int i = 0; i < 5; i++) v += xp[i] * wp[i];
  xh[((size_t)n * BB + b) * DD + lane] = f2bf(v);
  float si = wave_reduce_sum(v * att[64 + lane]);
  float sj = wave_reduce_sum(v * att[192 + lane]);
  if (lane == 0) { xi[pair] = si; xj[pair] = sj; }
}

// ---------------------------------------------------------------------------
// Kernel 5: alpha softmax + gathered weighted sum; out = gcn * emb  (bf16 store)
__global__ __launch_bounds__(256) void gcn_kernel(
    const int* __restrict__ src, const float* __restrict__ ei,
    const float* __restrict__ ej, const float* __restrict__ xi,
    const float* __restrict__ xj, const short* __restrict__ xh,
    const float* __restrict__ emb, short* __restrict__ outb) {
  int n = blockIdx.x, t = threadIdx.x;
  __shared__ int s_src[KK];
  __shared__ float s_ej[KK], s_xi[BB], s_alpha[KK][BB], s_emb[DD];
  if (t < KK) { int m = src[n * KK + t]; s_src[t] = m; s_ej[t] = ej[m]; }
  if (t >= 32 && t < 64) s_xi[t - 32] = xi[n * BB + (t - 32)];
  if (t >= 64 && t < 128) s_emb[t - 64] = emb[(size_t)n * DD + (t - 64)];
  __syncthreads();
  for (int idx = t; idx < KK * BB; idx += 256) {
    int k = idx >> 5, b = idx & 31;
    float a = ei[n] + s_xi[b] + s_ej[k] + xj[s_src[k] * BB + b];
    a = (a > 0.f) ? a : 0.2f * a;
    s_alpha[k][b] = a;
  }
  __syncthreads();
  if (t < BB) {
    float p[KK];
    float mx = -1e30f;
    #pragma unroll
    for (int k = 0; k < KK; k++) mx = fmaxf(mx, s_alpha[k][t]);
    float s = 0.f;
    #pragma unroll
    for (int k = 0; k < KK; k++) { p[k] = expf(s_alpha[k][t] - mx); s += p[k]; }
    float inv = 1.f / s;
    #pragma unroll
    for (int k = 0; k < KK; k++) s_alpha[k][t] = p[k] * inv;
  }
  __syncthreads();
  int b = t >> 3, d0 = (t & 7) * 8;
  float acc[8] = {};
  for (int k = 0; k < KK; k++) {
    float a = s_alpha[k][b];
    const short* p = xh + ((size_t)s_src[k] * BB + b) * DD + d0;
    s16x8 u = *(const s16x8*)p;
    #pragma unroll
    for (int j = 0; j < 8; j++) acc[j] += a * bf2f(u[j]);
  }
  short* op = outb + ((size_t)b * NN + n) * DD + d0;
  s16x8 o;
  #pragma unroll
  for (int j = 0; j < 8; j++) o[j] = f2bf(acc[j] * s_emb[d0 + j]);
  *(s16x8*)op = o;
}

// ---------------------------------------------------------------------------
// Kernel 6: MFMA MLP.  rows r = b*N+n (131072), y[r] = w2 @ relu(out[r]@w1^T + b1) + b2
__global__ __launch_bounds__(256) void mlp_mfma_kernel(
    const short* __restrict__ outb, const short* __restrict__ w1b,
    const float* __restrict__ b1, const float* __restrict__ w2,
    const float* __restrict__ b2, float* __restrict__ y) {
  int t = threadIdx.x;
  int w = t >> 6, l = t & 63;
  int lm = l & 15, lk = l >> 4;

  s16x8 bfrag[4][2];
  float b1v[4], w2v[4];
  #pragma unroll
  for (int j = 0; j < 4; j++) {
    int c = 64 * w + 16 * j + lm;
    #pragma unroll
    for (int s = 0; s < 2; s++)
      bfrag[j][s] = *(const s16x8*)(w1b + (size_t)c * DD + s * 32 + lk * 8);
    b1v[j] = b1[c];
    w2v[j] = w2[c];
  }
  float b2v = b2[0];
  __shared__ float part[4][64];
  size_t row_base = (size_t)blockIdx.x * 256;

  for (int chunk = 0; chunk < 4; chunk++) {
    size_t r0 = row_base + chunk * 64;
    f32x4 acc[4][4] = {};
    #pragma unroll
    for (int s = 0; s < 2; s++) {
      s16x8 afrag[4];
      #pragma unroll
      for (int i = 0; i < 4; i++) {
        size_t row = r0 + 16 * i + lm;
        afrag[i] = *(const s16x8*)(outb + row * DD + s * 32 + lk * 8);
      }
      #pragma unroll
      for (int i = 0; i < 4; i++)
        #pragma unroll
        for (int j = 0; j < 4; j++)
          acc[i][j] = __builtin_amdgcn_mfma_f32_16x16x32_bf16(
              afrag[i], bfrag[j][s], acc[i][j], 0, 0, 0);
    }
    float p[4][4];
    #pragma unroll
    for (int i = 0; i < 4; i++)
      #pragma unroll
      for (int r = 0; r < 4; r++) {
        float sum = 0.f;
        #pragma unroll
        for (int j = 0; j < 4; j++) {
          float h = acc[i][j][r] + b1v[j];
          h = fmaxf(h, 0.f);
          sum += h * w2v[j];
        }
        p[i][r] = sum;
      }
    #pragma unroll
    for (int off = 1; off < 16; off <<= 1)
      #pragma unroll
      for (int i = 0; i < 4; i++)
        #pragma unroll
        for (int r = 0; r < 4; r++)
          p[i][r] += __shfl_xor(p[i][r], off);
    if (lm == 0) {
      #pragma unroll
      for (int i = 0; i < 4; i++)
        #pragma unroll
        for (int r = 0; r < 4; r++)
          part[w][16 * i + 4 * lk + r] = p[i][r];
    }
    __syncthreads();
    if (t < 64)
      y[r0 + t] = b2v + part[0][t] + part[1][t] + part[2][t] + part[3][t];
    __syncthreads();
  }
}

// ---------------------------------------------------------------------------
extern "C" void kernel_launch(void* const* d_in, const int* in_sizes, int n_in,
                              void* d_out, int out_size, void* d_ws, size_t ws_size,
                              hipStream_t stream) {
  const float* x     = (const float*)d_in[0];
  const float* emb   = (const float*)d_in[1];
  const float* lin_w = (const float*)d_in[2];
  const float* att   = (const float*)d_in[3];
  const float* w1    = (const float*)d_in[4];
  const float* b1    = (const float*)d_in[5];
  const float* w2    = (const float*)d_in[6];
  const float* b2    = (const float*)d_in[7];
  float* y = (float*)d_out;

  char* ws = (char*)d_ws;
  // workspace layout (256B aligned), peak ~86.3 MB (ws is 256 MiB per harness poison)
  float* ne     = (float*)(ws + 0);          // N*D f32      = 1,048,576 B
  float* ei     = (float*)(ws + 1048576);    // N f32        =    16,384 B
  float* ej     = (float*)(ws + 1064960);    // N f32        =    16,384 B
  float* xi     = (float*)(ws + 1081344);    // N*B f32      =   524,288 B
  float* xj     = (float*)(ws + 1605632);    // N*B f32      =   524,288 B
  int*   srcbuf = (int*)  (ws + 2129920);    // N*K i32      =   245,760 B
  short* w1b    = (short*)(ws + 2375680);    // H*D bf16     =    32,768 B
  short* xh     = (short*)(ws + 2408448);    // N*B*D bf16   = 16,777,216 B
  float* simbuf = (float*)(ws + 19185664);   // N*N f32      = 67,108,864 B
  short* outb   = (short*)simbuf;            // overlay: sim fully consumed before outb written

  prep_kernel<<<NN / 4, 256, 0, stream>>>(emb, att, ne, ei, ej);
  w1cvt_kernel<<<(HH * DD) / 256, 256, 0, stream>>>(w1, w1b);
  xh_kernel<<<NN * BB / 4, 256, 0, stream>>>(x, lin_w, att, xh, xi, xj);

  dim3 g(64, 64);
  sim_kernel<<<g, 256, 0, stream>>>(ne, simbuf);
  topk_kernel<<<NN, 256, 0, stream>>>(simbuf, srcbuf);

  gcn_kernel<<<NN, 256, 0, stream>>>(srcbuf, ei, ej, xi, xj, xh, emb, outb);
  mlp_mfma_kernel<<<NN * BB / 256, 256, 0, stream>>>(outb, w1b, b1, w2, b2, y);
}

// Round 11
// 205.139 us; speedup vs baseline: 2.0517x; 1.1242x over previous
//
#include <hip/hip_runtime.h>
#include <hip/hip_bf16.h>
#include <math.h>

// Problem constants: N=4096 nodes, K=15 neighbors, D=64, IN=5, H=256 hidden, B=32 batch
#define NN 4096
#define KK 15
#define DD 64
#define HH 256
#define BB 32

typedef __attribute__((ext_vector_type(8))) short s16x8;   // 8 bf16 (MFMA A/B frag)
typedef __attribute__((ext_vector_type(4))) float f32x4;   // MFMA C/D frag

__device__ __forceinline__ float wave_reduce_sum(float v) {
  #pragma unroll
  for (int off = 1; off < 64; off <<= 1) v += __shfl_xor(v, off);
  return v;
}

__device__ __forceinline__ short f2bf(float f) {
  __hip_bfloat16 h = __float2bfloat16(f);
  return *reinterpret_cast<short*>(&h);
}
__device__ __forceinline__ float bf2f(short s) {
  unsigned u = ((unsigned)(unsigned short)s) << 16;
  return __uint_as_float(u);
}

// ---------------------------------------------------------------------------
// Kernel 1: ne = emb / (||emb|| + 1e-8);  e_i = emb @ att[0:64]; e_j = emb @ att[128:192]
__global__ __launch_bounds__(256) void prep_kernel(
    const float* __restrict__ emb, const float* __restrict__ att,
    float* __restrict__ ne, float* __restrict__ ei, float* __restrict__ ej) {
  int gid = blockIdx.x * 256 + threadIdx.x;
  int n = gid >> 6, lane = gid & 63;
  if (n >= NN) return;
  float v = emb[(size_t)n * DD + lane];
  float s2  = wave_reduce_sum(v * v);
  float sei = wave_reduce_sum(v * att[lane]);
  float sej = wave_reduce_sum(v * att[128 + lane]);
  ne[(size_t)n * DD + lane] = v / (sqrtf(s2) + 1e-8f);
  if (lane == 0) { ei[n] = sei; ej[n] = sej; }
}

// ---------------------------------------------------------------------------
// Kernel 2: sim tile GEMM (fp32 — top-k selection must stay exact)
__global__ __launch_bounds__(256) void sim_kernel(
    const float* __restrict__ ne, float* __restrict__ sim) {
  __shared__ float As[DD][68];
  __shared__ float Bs[DD][68];
  int t = threadIdx.x;
  int brow = blockIdx.y * 64;
  int bcol = blockIdx.x * 64;
  int lr = t >> 2, ldc = (t & 3) * 16;
  const float* pa = ne + (size_t)(brow + lr) * DD + ldc;
  const float* pb = ne + (size_t)(bcol + lr) * DD + ldc;
  #pragma unroll
  for (int j = 0; j < 16; j += 4) {
    float4 a = *(const float4*)(pa + j);
    float4 b = *(const float4*)(pb + j);
    float av[4] = {a.x, a.y, a.z, a.w};
    float bv[4] = {b.x, b.y, b.z, b.w};
    #pragma unroll
    for (int q = 0; q < 4; q++) {
      As[ldc + j + q][lr] = av[q];
      Bs[ldc + j + q][lr] = bv[q];
    }
  }
  __syncthreads();
  int tr = t >> 4, tc = t & 15;
  float acc[4][4] = {};
  #pragma unroll 16
  for (int k = 0; k < DD; k++) {
    float4 a = *(const float4*)&As[k][tr * 4];
    float4 b = *(const float4*)&Bs[k][tc * 4];
    float ar[4] = {a.x, a.y, a.z, a.w};
    float br[4] = {b.x, b.y, b.z, b.w};
    #pragma unroll
    for (int i = 0; i < 4; i++)
      #pragma unroll
      for (int j = 0; j < 4; j++)
        acc[i][j] += ar[i] * br[j];
  }
  int grow = brow + tr * 4;
  #pragma unroll
  for (int i = 0; i < 4; i++) {
    float4 o = {acc[i][0], acc[i][1], acc[i][2], acc[i][3]};
    *(float4*)(sim + (size_t)(grow + i) * NN + bcol + tc * 4) = o;
  }
}

// ---------------------------------------------------------------------------
// Kernel 3: EXACT top-15 per row via threshold selection.
// Stage 1: per-lane bitonic sort-16 on exact order-mapped u32 values; 6
//   merge-prune rounds (xor1,2 DPP; xor4,8,16,32 shfl) -> each wave's lanes
//   hold the wave's sorted top-16 values. 64 candidates to LDS.
// Stage 2: rank+eq count over the 64 cands -> v15 (exact 15th-largest value
//   of the row; cands provably contain the global top-15 multiset) and
//   c_gt = #{row > v15} (<= 14).
// Stage 3: lanes rescan registers: > thr -> emit col (atomic slot);
//   == thr -> tie list; thread 0 fills last 15-c_gt slots with smallest-col
//   ties (jax tie order). Output slot order is free: softmax+sum over k is
//   permutation-invariant.
__global__ __launch_bounds__(256) void topk_kernel(
    const float* __restrict__ sim, int* __restrict__ src) {
  int t = threadIdx.x;
  int n = blockIdx.x;
  const float* row = sim + (size_t)n * NN;

  __shared__ __align__(16) unsigned cand[64];
  __shared__ unsigned s_thr;
  __shared__ int s_cgt, s_cnt, s_tie_cnt;
  __shared__ int s_tie[64];
  if (t == 0) { s_cnt = 0; s_tie_cnt = 0; }

  // load 16 values/lane, coalesced: col(q) = ((q>>2)<<10) + t*4 + (q&3)
  unsigned k0[16];
  #pragma unroll
  for (int c = 0; c < 4; c++) {
    float4 f = *(const float4*)(row + c * 1024 + t * 4);
    float fv[4] = {f.x, f.y, f.z, f.w};
    #pragma unroll
    for (int e = 0; e < 4; e++) {
      unsigned u = __float_as_uint(fv[e]);
      k0[c * 4 + e] = u ^ ((unsigned)(((int)u) >> 31) | 0x80000000u);  // exact
    }
  }
  unsigned s[16];
  #pragma unroll
  for (int i = 0; i < 16; i++) s[i] = k0[i];

  // bitonic sort-16 descending (all indices compile-time)
  #pragma unroll
  for (int k = 2; k <= 16; k <<= 1) {
    #pragma unroll
    for (int j = k >> 1; j > 0; j >>= 1) {
      #pragma unroll
      for (int i = 0; i < 16; i++) {
        int ixj = i ^ j;
        if (ixj > i) {
          unsigned a = s[i], b = s[ixj];
          unsigned mx = (a > b) ? a : b;
          unsigned mn = (a > b) ? b : a;
          if ((i & k) == 0) { s[i] = mx; s[ixj] = mn; }
          else              { s[i] = mn; s[ixj] = mx; }
        }
      }
    }
  }

#define MERGE_ROUND(EXPR)                                                    \
  {                                                                          \
    unsigned p[16];                                                          \
    _Pragma("unroll")                                                        \
    for (int i = 0; i < 16; i++) { unsigned x = s[i]; p[i] = (unsigned)(EXPR); } \
    unsigned m[16];                                                          \
    _Pragma("unroll")                                                        \
    for (int i = 0; i < 16; i++) {                                           \
      unsigned q = p[15 - i];                                                \
      m[i] = (s[i] > q) ? s[i] : q;                                          \
    }                                                                        \
    _Pragma("unroll")                                                        \
    for (int j = 8; j > 0; j >>= 1) {                                        \
      _Pragma("unroll")                                                      \
      for (int i = 0; i < 16; i++) {                                         \
        int ixj = i ^ j;                                                     \
        if (ixj > i) {                                                       \
          unsigned a = m[i], b = m[ixj];                                     \
          m[i]   = (a > b) ? a : b;                                          \
          m[ixj] = (a > b) ? b : a;                                          \
        }                                                                    \
      }                                                                      \
    }                                                                        \
    _Pragma("unroll")                                                        \
    for (int i = 0; i < 16; i++) s[i] = m[i];                                \
  }

  MERGE_ROUND(__builtin_amdgcn_update_dpp(0, (int)x, 0xB1, 0xF, 0xF, true))  // xor1
  MERGE_ROUND(__builtin_amdgcn_update_dpp(0, (int)x, 0x4E, 0xF, 0xF, true))  // xor2
  MERGE_ROUND(__shfl_xor((int)x, 4))
  MERGE_ROUND(__shfl_xor((int)x, 8))
  MERGE_ROUND(__shfl_xor((int)x, 16))
  MERGE_ROUND(__shfl_xor((int)x, 32))
#undef MERGE_ROUND

  int wv = t >> 6, l = t & 63;
  if (l == 0) {
    #pragma unroll
    for (int i = 0; i < 16; i++) cand[wv * 16 + i] = s[i];
  }
  __syncthreads();

  // stage 2: v15 = unique value with strict-rank r<=14 and r+eq>=15
  if (t < 64) {
    unsigned my = cand[t];
    int r = 0, eq = 0;
    #pragma unroll
    for (int i = 0; i < 64; i += 4) {
      uint4 c4 = *(const uint4*)&cand[i];
      r  += (c4.x > my) + (c4.y > my) + (c4.z > my) + (c4.w > my);
      eq += (c4.x == my) + (c4.y == my) + (c4.z == my) + (c4.w == my);
    }
    if (r <= 14 && r + eq >= 15) { s_thr = my; s_cgt = r; }  // benign multi-write
  }
  __syncthreads();

  unsigned thr = s_thr;
  // stage 3: winners (> thr, exactly c_gt of them) + tie candidates (== thr)
  #pragma unroll
  for (int q = 0; q < 16; q++) {
    unsigned kv = k0[q];
    if (kv > thr) {
      int slot = atomicAdd(&s_cnt, 1);
      src[n * KK + slot] = ((q >> 2) << 10) + t * 4 + (q & 3);
    } else if (kv == thr) {
      int ts = atomicAdd(&s_tie_cnt, 1);
      if (ts < 64) s_tie[ts] = ((q >> 2) << 10) + t * 4 + (q & 3);
    }
  }
  __syncthreads();
  if (t == 0) {
    int cgt = s_cgt;
    int tn = s_tie_cnt; if (tn > 64) tn = 64;
    for (int slot = cgt; slot < KK; slot++) {   // fill with smallest-col ties
      int best = 1 << 30, bi = 0;
      for (int i = 0; i < tn; i++)
        if (s_tie[i] < best) { best = s_tie[i]; bi = i; }
      src[n * KK + slot] = best;
      s_tie[bi] = 1 << 30;
    }
  }
}

// ---------------------------------------------------------------------------
// Kernel 4: xh (bf16 store) + xi/xj (fp32); tail blocks convert w1 -> bf16
__global__ __launch_bounds__(256) void xh_kernel(
    const float* __restrict__ x, const float* __restrict__ lin_w,
    const float* __restrict__ att, short* __restrict__ xh,
    float* __restrict__ xi, float* __restrict__ xj,
    const float* __restrict__ w1, short* __restrict__ w1b) {
  if (blockIdx.x >= NN * BB / 4) {  // 64 tail blocks: w1 conversion
    int i = (blockIdx.x - NN * BB / 4) * 256 + threadIdx.x;
    w1b[i] = f2bf(w1[i]);
    return;
  }
  int gid = blockIdx.x * 256 + threadIdx.x;
  int pair = gid >> 6, lane = gid & 63;
  int n = pair >> 5, b = pair & 31;
  const float* xp = x + ((size_t)b * NN + n) * 5;
  const float* wp = lin_w + lane * 5;
  float v = 0.f;
  #pragma unroll
  for (int i = 0; i < 5; i++) v += xp[i] * wp[i];
  xh[((size_t)n * BB + b) * DD + lane] = f2bf(v);
  float si = wave_reduce_sum(v * att[64 + lane]);
  float sj = wave_reduce_sum(v * att[192 + lane]);
  if (lane == 0) { xi[pair] = si; xj[pair] = sj; }
}

// ---------------------------------------------------------------------------
// Kernel 5: alpha softmax + gathered weighted sum; out = gcn * emb  (bf16 store)
__global__ __launch_bounds__(256) void gcn_kernel(
    const int* __restrict__ src, const float* __restrict__ ei,
    const float* __restrict__ ej, const float* __restrict__ xi,
    const float* __restrict__ xj, const short* __restrict__ xh,
    const float* __restrict__ emb, short* __restrict__ outb) {
  int n = blockIdx.x, t = threadIdx.x;
  __shared__ int s_src[KK];
  __shared__ float s_ej[KK], s_xi[BB], s_alpha[KK][BB], s_emb[DD];
  if (t < KK) { int m = src[n * KK + t]; s_src[t] = m; s_ej[t] = ej[m]; }
  if (t >= 32 && t < 64) s_xi[t - 32] = xi[n * BB + (t - 32)];
  if (t >= 64 && t < 128) s_emb[t - 64] = emb[(size_t)n * DD + (t - 64)];
  __syncthreads();
  for (int idx = t; idx < KK * BB; idx += 256) {
    int k = idx >> 5, b = idx & 31;
    float a = ei[n] + s_xi[b] + s_ej[k] + xj[s_src[k] * BB + b];
    a = (a > 0.f) ? a : 0.2f * a;
    s_alpha[k][b] = a;
  }
  __syncthreads();
  if (t < BB) {
    float p[KK];
    float mx = -1e30f;
    #pragma unroll
    for (int k = 0; k < KK; k++) mx = fmaxf(mx, s_alpha[k][t]);
    float s = 0.f;
    #pragma unroll
    for (int k = 0; k < KK; k++) { p[k] = expf(s_alpha[k][t] - mx); s += p[k]; }
    float inv = 1.f / s;
    #pragma unroll
    for (int k = 0; k < KK; k++) s_alpha[k][t] = p[k] * inv;
  }
  __syncthreads();
  int b = t >> 3, d0 = (t & 7) * 8;
  float acc[8] = {};
  for (int k = 0; k < KK; k++) {
    float a = s_alpha[k][b];
    const short* p = xh + ((size_t)s_src[k] * BB + b) * DD + d0;
    s16x8 u = *(const s16x8*)p;
    #pragma unroll
    for (int j = 0; j < 8; j++) acc[j] += a * bf2f(u[j]);
  }
  short* op = outb + ((size_t)b * NN + n) * DD + d0;
  s16x8 o;
  #pragma unroll
  for (int j = 0; j < 8; j++) o[j] = f2bf(acc[j] * s_emb[d0 + j]);
  *(s16x8*)op = o;
}

// ---------------------------------------------------------------------------
// Kernel 6: MFMA MLP.  rows r = b*N+n (131072), y[r] = w2 @ relu(out[r]@w1^T + b1) + b2
__global__ __launch_bounds__(256) void mlp_mfma_kernel(
    const short* __restrict__ outb, const short* __restrict__ w1b,
    const float* __restrict__ b1, const float* __restrict__ w2,
    const float* __restrict__ b2, float* __restrict__ y) {
  int t = threadIdx.x;
  int w = t >> 6, l = t & 63;
  int lm = l & 15, lk = l >> 4;

  s16x8 bfrag[4][2];
  float b1v[4], w2v[4];
  #pragma unroll
  for (int j = 0; j < 4; j++) {
    int c = 64 * w + 16 * j + lm;
    #pragma unroll
    for (int s = 0; s < 2; s++)
      bfrag[j][s] = *(const s16x8*)(w1b + (size_t)c * DD + s * 32 + lk * 8);
    b1v[j] = b1[c];
    w2v[j] = w2[c];
  }
  float b2v = b2[0];
  __shared__ float part[4][64];
  size_t row_base = (size_t)blockIdx.x * 256;

  for (int chunk = 0; chunk < 4; chunk++) {
    size_t r0 = row_base + chunk * 64;
    f32x4 acc[4][4] = {};
    #pragma unroll
    for (int s = 0; s < 2; s++) {
      s16x8 afrag[4];
      #pragma unroll
      for (int i = 0; i < 4; i++) {
        size_t row = r0 + 16 * i + lm;
        afrag[i] = *(const s16x8*)(outb + row * DD + s * 32 + lk * 8);
      }
      #pragma unroll
      for (int i = 0; i < 4; i++)
        #pragma unroll
        for (int j = 0; j < 4; j++)
          acc[i][j] = __builtin_amdgcn_mfma_f32_16x16x32_bf16(
              afrag[i], bfrag[j][s], acc[i][j], 0, 0, 0);
    }
    float p[4][4];
    #pragma unroll
    for (int i = 0; i < 4; i++)
      #pragma unroll
      for (int r = 0; r < 4; r++) {
        float sum = 0.f;
        #pragma unroll
        for (int j = 0; j < 4; j++) {
          float h = acc[i][j][r] + b1v[j];
          h = fmaxf(h, 0.f);
          sum += h * w2v[j];
        }
        p[i][r] = sum;
      }
    #pragma unroll
    for (int off = 1; off < 16; off <<= 1)
      #pragma unroll
      for (int i = 0; i < 4; i++)
        #pragma unroll
        for (int r = 0; r < 4; r++)
          p[i][r] += __shfl_xor(p[i][r], off);
    if (lm == 0) {
      #pragma unroll
      for (int i = 0; i < 4; i++)
        #pragma unroll
        for (int r = 0; r < 4; r++)
          part[w][16 * i + 4 * lk + r] = p[i][r];
    }
    __syncthreads();
    if (t < 64)
      y[r0 + t] = b2v + part[0][t] + part[1][t] + part[2][t] + part[3][t];
    __syncthreads();
  }
}

// ---------------------------------------------------------------------------
extern "C" void kernel_launch(void* const* d_in, const int* in_sizes, int n_in,
                              void* d_out, int out_size, void* d_ws, size_t ws_size,
                              hipStream_t stream) {
  const float* x     = (const float*)d_in[0];
  const float* emb   = (const float*)d_in[1];
  const float* lin_w = (const float*)d_in[2];
  const float* att   = (const float*)d_in[3];
  const float* w1    = (const float*)d_in[4];
  const float* b1    = (const float*)d_in[5];
  const float* w2    = (const float*)d_in[6];
  const float* b2    = (const float*)d_in[7];
  float* y = (float*)d_out;

  char* ws = (char*)d_ws;
  // workspace layout (256B aligned), peak ~86.3 MB (ws is 256 MiB per harness poison)
  float* ne     = (float*)(ws + 0);          // N*D f32      = 1,048,576 B
  float* ei     = (float*)(ws + 1048576);    // N f32        =    16,384 B
  float* ej     = (float*)(ws + 1064960);    // N f32        =    16,384 B
  float* xi     = (float*)(ws + 1081344);    // N*B f32      =   524,288 B
  float* xj     = (float*)(ws + 1605632);    // N*B f32      =   524,288 B
  int*   srcbuf = (int*)  (ws + 2129920);    // N*K i32      =   245,760 B
  short* w1b    = (short*)(ws + 2375680);    // H*D bf16     =    32,768 B
  short* xh     = (short*)(ws + 2408448);    // N*B*D bf16   = 16,777,216 B
  float* simbuf = (float*)(ws + 19185664);   // N*N f32      = 67,108,864 B
  short* outb   = (short*)simbuf;            // overlay: sim fully consumed before outb written

  prep_kernel<<<NN / 4, 256, 0, stream>>>(emb, att, ne, ei, ej);
  xh_kernel<<<NN * BB / 4 + 64, 256, 0, stream>>>(x, lin_w, att, xh, xi, xj, w1, w1b);

  dim3 g(64, 64);
  sim_kernel<<<g, 256, 0, stream>>>(ne, simbuf);
  topk_kernel<<<NN, 256, 0, stream>>>(simbuf, srcbuf);

  gcn_kernel<<<NN, 256, 0, stream>>>(srcbuf, ei, ej, xi, xj, xh, emb, outb);
  mlp_mfma_kernel<<<NN * BB / 256, 256, 0, stream>>>(outb, w1b, b1, w2, b2, y);
}

// Round 13
// 201.289 us; speedup vs baseline: 2.0910x; 1.0191x over previous
//
#include <hip/hip_runtime.h>
#include <hip/hip_bf16.h>
#include <math.h>

// Problem constants: N=4096 nodes, K=15 neighbors, D=64, IN=5, H=256 hidden, B=32 batch
#define NN 4096
#define KK 15
#define DD 64
#define HH 256
#define BB 32

typedef __attribute__((ext_vector_type(8))) short s16x8;   // 8 bf16 (MFMA A/B frag)
typedef __attribute__((ext_vector_type(4))) float f32x4;   // MFMA C/D frag

__device__ __forceinline__ float wave_reduce_sum(float v) {
  #pragma unroll
  for (int off = 1; off < 64; off <<= 1) v += __shfl_xor(v, off);
  return v;
}

__device__ __forceinline__ short f2bf(float f) {
  __hip_bfloat16 h = __float2bfloat16(f);
  return *reinterpret_cast<short*>(&h);
}
__device__ __forceinline__ float bf2f(short s) {
  unsigned u = ((unsigned)(unsigned short)s) << 16;
  return __uint_as_float(u);
}

// ---------------------------------------------------------------------------
// Kernel 1 (fused front): three block roles:
//   [0, 32768)        xh: xh[n][b][:] = lin_w @ x[b][n][:], bf16; xi/xj dots
//   [32768, 32832)    w1 -> bf16
//   [32832, 33856)    prep: ne = emb/||emb||; e_i, e_j dots
__global__ __launch_bounds__(256) void front_kernel(
    const float* __restrict__ x, const float* __restrict__ lin_w,
    const float* __restrict__ att, short* __restrict__ xh,
    float* __restrict__ xi, float* __restrict__ xj,
    const float* __restrict__ w1, short* __restrict__ w1b,
    const float* __restrict__ emb, float* __restrict__ ne,
    float* __restrict__ ei, float* __restrict__ ej) {
  int bid = blockIdx.x;
  int t = threadIdx.x;
  if (bid >= NN * BB / 4 + 64) {           // prep role
    int gid = (bid - (NN * BB / 4 + 64)) * 256 + t;
    int n = gid >> 6, lane = gid & 63;
    float v = emb[(size_t)n * DD + lane];
    float s2  = wave_reduce_sum(v * v);
    float sei = wave_reduce_sum(v * att[lane]);
    float sej = wave_reduce_sum(v * att[128 + lane]);
    ne[(size_t)n * DD + lane] = v / (sqrtf(s2) + 1e-8f);
    if (lane == 0) { ei[n] = sei; ej[n] = sej; }
    return;
  }
  if (bid >= NN * BB / 4) {                // w1cvt role
    int i = (bid - NN * BB / 4) * 256 + t;
    w1b[i] = f2bf(w1[i]);
    return;
  }
  int gid = bid * 256 + t;                 // xh role
  int pair = gid >> 6, lane = gid & 63;
  int n = pair >> 5, b = pair & 31;
  const float* xp = x + ((size_t)b * NN + n) * 5;
  const float* wp = lin_w + lane * 5;
  float v = 0.f;
  #pragma unroll
  for (int i = 0; i < 5; i++) v += xp[i] * wp[i];
  xh[((size_t)n * BB + b) * DD + lane] = f2bf(v);
  float si = wave_reduce_sum(v * att[64 + lane]);
  float sj = wave_reduce_sum(v * att[192 + lane]);
  if (lane == 0) { xi[pair] = si; xj[pair] = sj; }
}

// ---------------------------------------------------------------------------
// Kernel 2: sim tile GEMM (fp32 — selection must stay fp32-exact)
__global__ __launch_bounds__(256) void sim_kernel(
    const float* __restrict__ ne, float* __restrict__ sim) {
  __shared__ float As[DD][68];
  __shared__ float Bs[DD][68];
  int t = threadIdx.x;
  int brow = blockIdx.y * 64;
  int bcol = blockIdx.x * 64;
  int lr = t >> 2, ldc = (t & 3) * 16;
  const float* pa = ne + (size_t)(brow + lr) * DD + ldc;
  const float* pb = ne + (size_t)(bcol + lr) * DD + ldc;
  #pragma unroll
  for (int j = 0; j < 16; j += 4) {
    float4 a = *(const float4*)(pa + j);
    float4 b = *(const float4*)(pb + j);
    float av[4] = {a.x, a.y, a.z, a.w};
    float bv[4] = {b.x, b.y, b.z, b.w};
    #pragma unroll
    for (int q = 0; q < 4; q++) {
      As[ldc + j + q][lr] = av[q];
      Bs[ldc + j + q][lr] = bv[q];
    }
  }
  __syncthreads();
  int tr = t >> 4, tc = t & 15;
  float acc[4][4] = {};
  #pragma unroll 16
  for (int k = 0; k < DD; k++) {
    float4 a = *(const float4*)&As[k][tr * 4];
    float4 b = *(const float4*)&Bs[k][tc * 4];
    float ar[4] = {a.x, a.y, a.z, a.w};
    float br[4] = {b.x, b.y, b.z, b.w};
    #pragma unroll
    for (int i = 0; i < 4; i++)
      #pragma unroll
      for (int j = 0; j < 4; j++)
        acc[i][j] += ar[i] * br[j];
  }
  int grow = brow + tr * 4;
  #pragma unroll
  for (int i = 0; i < 4; i++) {
    float4 o = {acc[i][0], acc[i][1], acc[i][2], acc[i][3]};
    *(float4*)(sim + (size_t)(grow + i) * NN + bcol + tc * 4) = o;
  }
}

// ---------------------------------------------------------------------------
// Kernel 3: EXACT top-15 per row via threshold selection (round-11, passing).
__global__ __launch_bounds__(256) void topk_kernel(
    const float* __restrict__ sim, int* __restrict__ src) {
  int t = threadIdx.x;
  int n = blockIdx.x;
  const float* row = sim + (size_t)n * NN;

  __shared__ __align__(16) unsigned cand[64];
  __shared__ unsigned s_thr;
  __shared__ int s_cgt, s_cnt, s_tie_cnt;
  __shared__ int s_tie[64];
  if (t == 0) { s_cnt = 0; s_tie_cnt = 0; }

  unsigned k0[16];
  #pragma unroll
  for (int c = 0; c < 4; c++) {
    float4 f = *(const float4*)(row + c * 1024 + t * 4);
    float fv[4] = {f.x, f.y, f.z, f.w};
    #pragma unroll
    for (int e = 0; e < 4; e++) {
      unsigned u = __float_as_uint(fv[e]);
      k0[c * 4 + e] = u ^ ((unsigned)(((int)u) >> 31) | 0x80000000u);  // exact
    }
  }
  unsigned s[16];
  #pragma unroll
  for (int i = 0; i < 16; i++) s[i] = k0[i];

  // bitonic sort-16 descending
  #pragma unroll
  for (int k = 2; k <= 16; k <<= 1) {
    #pragma unroll
    for (int j = k >> 1; j > 0; j >>= 1) {
      #pragma unroll
      for (int i = 0; i < 16; i++) {
        int ixj = i ^ j;
        if (ixj > i) {
          unsigned a = s[i], b = s[ixj];
          unsigned mx = (a > b) ? a : b;
          unsigned mn = (a > b) ? b : a;
          if ((i & k) == 0) { s[i] = mx; s[ixj] = mn; }
          else              { s[i] = mn; s[ixj] = mx; }
        }
      }
    }
  }

#define MERGE_ROUND(EXPR)                                                    \
  {                                                                          \
    unsigned p[16];                                                          \
    _Pragma("unroll")                                                        \
    for (int i = 0; i < 16; i++) { unsigned x = s[i]; p[i] = (unsigned)(EXPR); } \
    unsigned m[16];                                                          \
    _Pragma("unroll")                                                        \
    for (int i = 0; i < 16; i++) {                                           \
      unsigned q = p[15 - i];                                                \
      m[i] = (s[i] > q) ? s[i] : q;                                          \
    }                                                                        \
    _Pragma("unroll")                                                        \
    for (int j = 8; j > 0; j >>= 1) {                                        \
      _Pragma("unroll")                                                      \
      for (int i = 0; i < 16; i++) {                                         \
        int ixj = i ^ j;                                                     \
        if (ixj > i) {                                                       \
          unsigned a = m[i], b = m[ixj];                                     \
          m[i]   = (a > b) ? a : b;                                          \
          m[ixj] = (a > b) ? b : a;                                          \
        }                                                                    \
      }                                                                      \
    }                                                                        \
    _Pragma("unroll")                                                        \
    for (int i = 0; i < 16; i++) s[i] = m[i];                                \
  }

  MERGE_ROUND(__builtin_amdgcn_update_dpp(0, (int)x, 0xB1, 0xF, 0xF, true))  // xor1
  MERGE_ROUND(__builtin_amdgcn_update_dpp(0, (int)x, 0x4E, 0xF, 0xF, true))  // xor2
  MERGE_ROUND(__shfl_xor((int)x, 4))
  MERGE_ROUND(__shfl_xor((int)x, 8))
  MERGE_ROUND(__shfl_xor((int)x, 16))
  MERGE_ROUND(__shfl_xor((int)x, 32))
#undef MERGE_ROUND

  int wv = t >> 6, l = t & 63;
  if (l == 0) {
    #pragma unroll
    for (int i = 0; i < 16; i++) cand[wv * 16 + i] = s[i];
  }
  __syncthreads();

  if (t < 64) {
    unsigned my = cand[t];
    int r = 0, eq = 0;
    #pragma unroll
    for (int i = 0; i < 64; i += 4) {
      uint4 c4 = *(const uint4*)&cand[i];
      r  += (c4.x > my) + (c4.y > my) + (c4.z > my) + (c4.w > my);
      eq += (c4.x == my) + (c4.y == my) + (c4.z == my) + (c4.w == my);
    }
    if (r <= 14 && r + eq >= 15) { s_thr = my; s_cgt = r; }  // benign multi-write
  }
  __syncthreads();

  unsigned thr = s_thr;
  #pragma unroll
  for (int q = 0; q < 16; q++) {
    unsigned kv = k0[q];
    if (kv > thr) {
      int slot = atomicAdd(&s_cnt, 1);
      src[n * KK + slot] = ((q >> 2) << 10) + t * 4 + (q & 3);
    } else if (kv == thr) {
      int ts = atomicAdd(&s_tie_cnt, 1);
      if (ts < 64) s_tie[ts] = ((q >> 2) << 10) + t * 4 + (q & 3);
    }
  }
  __syncthreads();
  if (t == 0) {
    int cgt = s_cgt;
    int tn = s_tie_cnt; if (tn > 64) tn = 64;
    for (int slot = cgt; slot < KK; slot++) {
      int best = 1 << 30, bi = 0;
      for (int i = 0; i < tn; i++)
        if (s_tie[i] < best) { best = s_tie[i]; bi = i; }
      src[n * KK + slot] = best;
      s_tie[bi] = 1 << 30;
    }
  }
}

// ---------------------------------------------------------------------------
// Kernel 4 (fused gcn+mlp), one block per node n:
//  Phase A: alpha softmax + gather-accumulate -> out[b][d] (32x64) * emb[n]
//  bf16-pack into XOR-swizzled LDS (slot = (t&~7)|((t&7)^(b&7)))
//  Phase B: (32x64)@w1^T via MFMA, +b1, relu, .w2 -> y[b*N+n] for 32 b's.
// Numerics identical to the split version (same bf16 rounding points).
__global__ __launch_bounds__(256) void gcn_mlp_kernel(
    const int* __restrict__ src, const float* __restrict__ ei,
    const float* __restrict__ ej, const float* __restrict__ xi,
    const float* __restrict__ xj, const short* __restrict__ xh,
    const float* __restrict__ emb, const short* __restrict__ w1b,
    const float* __restrict__ b1, const float* __restrict__ w2,
    const float* __restrict__ b2, float* __restrict__ y) {
  int n = blockIdx.x, t = threadIdx.x;
  int w = t >> 6, l = t & 63;
  int lm = l & 15, lk = l >> 4;

  // B-operand fragments: wave w owns hidden cols 64w..64w+63
  s16x8 bfrag[4][2];
  float b1v[4], w2v[4];
  #pragma unroll
  for (int j = 0; j < 4; j++) {
    int c = 64 * w + 16 * j + lm;
    #pragma unroll
    for (int s = 0; s < 2; s++)
      bfrag[j][s] = *(const s16x8*)(w1b + (size_t)c * DD + s * 32 + lk * 8);
    b1v[j] = b1[c];
    w2v[j] = w2[c];
  }
  float b2v = b2[0];

  __shared__ int s_src[KK];
  __shared__ float s_ej[KK], s_xi[BB], s_alpha[KK][BB], s_emb[DD];
  __shared__ __align__(16) short out_lds[256 * 8];  // 4 KB, swizzled 16B slots
  __shared__ float part[4][32];

  if (t < KK) { int m = src[n * KK + t]; s_src[t] = m; s_ej[t] = ej[m]; }
  if (t >= 32 && t < 64) s_xi[t - 32] = xi[n * BB + (t - 32)];
  if (t >= 64 && t < 128) s_emb[t - 64] = emb[(size_t)n * DD + (t - 64)];
  __syncthreads();
  for (int idx = t; idx < KK * BB; idx += 256) {
    int k = idx >> 5, b = idx & 31;
    float a = ei[n] + s_xi[b] + s_ej[k] + xj[s_src[k] * BB + b];
    a = (a > 0.f) ? a : 0.2f * a;
    s_alpha[k][b] = a;
  }
  __syncthreads();
  if (t < BB) {
    float p[KK];
    float mx = -1e30f;
    #pragma unroll
    for (int k = 0; k < KK; k++) mx = fmaxf(mx, s_alpha[k][t]);
    float s = 0.f;
    #pragma unroll
    for (int k = 0; k < KK; k++) { p[k] = expf(s_alpha[k][t] - mx); s += p[k]; }
    float inv = 1.f / s;
    #pragma unroll
    for (int k = 0; k < KK; k++) s_alpha[k][t] = p[k] * inv;
  }
  __syncthreads();
  {
    int b = t >> 3, d0 = (t & 7) * 8;
    float acc[8] = {};
    for (int k = 0; k < KK; k++) {
      float a = s_alpha[k][b];
      const short* p = xh + ((size_t)s_src[k] * BB + b) * DD + d0;
      s16x8 u = *(const s16x8*)p;
      #pragma unroll
      for (int j = 0; j < 8; j++) acc[j] += a * bf2f(u[j]);
    }
    s16x8 o;
    #pragma unroll
    for (int j = 0; j < 8; j++) o[j] = f2bf(acc[j] * s_emb[d0 + j]);
    int slot = (t & ~7) | ((t & 7) ^ ((t >> 3) & 7));
    *(s16x8*)&out_lds[slot * 8] = o;
  }
  __syncthreads();

  // Phase B: A(32x64) @ w1^T. A-frag lane l, row-tile i, k-half s:
  //   row b = 16i+lm, k-bytes owned by phase-A thread t' = b*8 + (4s+lk)
  f32x4 acc2[2][4] = {};
  #pragma unroll
  for (int s = 0; s < 2; s++) {
    s16x8 afrag[2];
    #pragma unroll
    for (int i = 0; i < 2; i++) {
      int bb = 16 * i + lm;
      int jj = 4 * s + lk;
      int sl = bb * 8 + (jj ^ (bb & 7));
      afrag[i] = *(const s16x8*)&out_lds[sl * 8];
    }
    #pragma unroll
    for (int i = 0; i < 2; i++)
      #pragma unroll
      for (int j = 0; j < 4; j++)
        acc2[i][j] = __builtin_amdgcn_mfma_f32_16x16x32_bf16(
            afrag[i], bfrag[j][s], acc2[i][j], 0, 0, 0);
  }
  // epilogue: relu + w2-weighted col sum, reduce over 16 col-lanes (lm)
  float p[2][4];
  #pragma unroll
  for (int i = 0; i < 2; i++)
    #pragma unroll
    for (int r = 0; r < 4; r++) {
      float sum = 0.f;
      #pragma unroll
      for (int j = 0; j < 4; j++) {
        float h = acc2[i][j][r] + b1v[j];
        h = fmaxf(h, 0.f);
        sum += h * w2v[j];
      }
      p[i][r] = sum;
    }
  #pragma unroll
  for (int off = 1; off < 16; off <<= 1)
    #pragma unroll
    for (int i = 0; i < 2; i++)
      #pragma unroll
      for (int r = 0; r < 4; r++)
        p[i][r] += __shfl_xor(p[i][r], off);
  if (lm == 0) {
    #pragma unroll
    for (int i = 0; i < 2; i++)
      #pragma unroll
      for (int r = 0; r < 4; r++)
        part[w][16 * i + 4 * lk + r] = p[i][r];
  }
  __syncthreads();
  if (t < BB)
    y[(size_t)t * NN + n] = b2v + part[0][t] + part[1][t] + part[2][t] + part[3][t];
}

// ---------------------------------------------------------------------------
extern "C" void kernel_launch(void* const* d_in, const int* in_sizes, int n_in,
                              void* d_out, int out_size, void* d_ws, size_t ws_size,
                              hipStream_t stream) {
  const float* x     = (const float*)d_in[0];
  const float* emb   = (const float*)d_in[1];
  const float* lin_w = (const float*)d_in[2];
  const float* att   = (const float*)d_in[3];
  const float* w1    = (const float*)d_in[4];
  const float* b1    = (const float*)d_in[5];
  const float* w2    = (const float*)d_in[6];
  const float* b2    = (const float*)d_in[7];
  float* y = (float*)d_out;

  char* ws = (char*)d_ws;
  // workspace layout (256B aligned), peak ~86.3 MB
  float* ne     = (float*)(ws + 0);          // N*D f32      = 1,048,576 B
  float* ei     = (float*)(ws + 1048576);    // N f32        =    16,384 B
  float* ej     = (float*)(ws + 1064960);    // N f32        =    16,384 B
  float* xi     = (float*)(ws + 1081344);    // N*B f32      =   524,288 B
  float* xj     = (float*)(ws + 1605632);    // N*B f32      =   524,288 B
  int*   srcbuf = (int*)  (ws + 2129920);    // N*K i32      =   245,760 B
  short* w1b    = (short*)(ws + 2375680);    // H*D bf16     =    32,768 B
  short* xh     = (short*)(ws + 2408448);    // N*B*D bf16   = 16,777,216 B
  float* simbuf = (float*)(ws + 19185664);   // N*N f32      = 67,108,864 B

  front_kernel<<<NN * BB / 4 + 64 + NN / 4, 256, 0, stream>>>(
      x, lin_w, att, xh, xi, xj, w1, w1b, emb, ne, ei, ej);

  dim3 g(64, 64);
  sim_kernel<<<g, 256, 0, stream>>>(ne, simbuf);
  topk_kernel<<<NN, 256, 0, stream>>>(simbuf, srcbuf);

  gcn_mlp_kernel<<<NN, 256, 0, stream>>>(srcbuf, ei, ej, xi, xj, xh, emb,
                                         w1b, b1, w2, b2, y);
}

// Round 14
// 194.600 us; speedup vs baseline: 2.1628x; 1.0344x over previous
//
#include <hip/hip_runtime.h>
#include <hip/hip_bf16.h>
#include <math.h>

// Problem constants: N=4096 nodes, K=15 neighbors, D=64, IN=5, H=256 hidden, B=32 batch
#define NN 4096
#define KK 15
#define DD 64
#define HH 256
#define BB 32

typedef __attribute__((ext_vector_type(8))) short s16x8;   // 8 bf16 (MFMA A/B frag)
typedef __attribute__((ext_vector_type(4))) float f32x4;   // MFMA C/D frag

__device__ __forceinline__ float wave_reduce_sum(float v) {
  #pragma unroll
  for (int off = 1; off < 64; off <<= 1) v += __shfl_xor(v, off);
  return v;
}

__device__ __forceinline__ short f2bf(float f) {
  __hip_bfloat16 h = __float2bfloat16(f);
  return *reinterpret_cast<short*>(&h);
}
__device__ __forceinline__ float bf2f(short s) {
  unsigned u = ((unsigned)(unsigned short)s) << 16;
  return __uint_as_float(u);
}

// ---------------------------------------------------------------------------
// Kernel 1 (fused front): three block roles:
//   [0, 32768)        xh: xh[n][b][:] = lin_w @ x[b][n][:], bf16; xi/xj dots
//   [32768, 32832)    w1 -> bf16
//   [32832, 33856)    prep: ne = emb/||emb||; e_i, e_j dots
__global__ __launch_bounds__(256) void front_kernel(
    const float* __restrict__ x, const float* __restrict__ lin_w,
    const float* __restrict__ att, short* __restrict__ xh,
    float* __restrict__ xi, float* __restrict__ xj,
    const float* __restrict__ w1, short* __restrict__ w1b,
    const float* __restrict__ emb, float* __restrict__ ne,
    float* __restrict__ ei, float* __restrict__ ej) {
  int bid = blockIdx.x;
  int t = threadIdx.x;
  if (bid >= NN * BB / 4 + 64) {           // prep role
    int gid = (bid - (NN * BB / 4 + 64)) * 256 + t;
    int n = gid >> 6, lane = gid & 63;
    float v = emb[(size_t)n * DD + lane];
    float s2  = wave_reduce_sum(v * v);
    float sei = wave_reduce_sum(v * att[lane]);
    float sej = wave_reduce_sum(v * att[128 + lane]);
    ne[(size_t)n * DD + lane] = v / (sqrtf(s2) + 1e-8f);
    if (lane == 0) { ei[n] = sei; ej[n] = sej; }
    return;
  }
  if (bid >= NN * BB / 4) {                // w1cvt role
    int i = (bid - NN * BB / 4) * 256 + t;
    w1b[i] = f2bf(w1[i]);
    return;
  }
  int gid = bid * 256 + t;                 // xh role
  int pair = gid >> 6, lane = gid & 63;
  int n = pair >> 5, b = pair & 31;
  const float* xp = x + ((size_t)b * NN + n) * 5;
  const float* wp = lin_w + lane * 5;
  float v = 0.f;
  #pragma unroll
  for (int i = 0; i < 5; i++) v += xp[i] * wp[i];
  xh[((size_t)n * BB + b) * DD + lane] = f2bf(v);
  float si = wave_reduce_sum(v * att[64 + lane]);
  float sj = wave_reduce_sum(v * att[192 + lane]);
  if (lane == 0) { xi[pair] = si; xj[pair] = sj; }
}

// ---------------------------------------------------------------------------
// Kernel 2: sim tile GEMM (fp32 — selection must stay fp32-exact)
__global__ __launch_bounds__(256) void sim_kernel(
    const float* __restrict__ ne, float* __restrict__ sim) {
  __shared__ float As[DD][68];
  __shared__ float Bs[DD][68];
  int t = threadIdx.x;
  int brow = blockIdx.y * 64;
  int bcol = blockIdx.x * 64;
  int lr = t >> 2, ldc = (t & 3) * 16;
  const float* pa = ne + (size_t)(brow + lr) * DD + ldc;
  const float* pb = ne + (size_t)(bcol + lr) * DD + ldc;
  #pragma unroll
  for (int j = 0; j < 16; j += 4) {
    float4 a = *(const float4*)(pa + j);
    float4 b = *(const float4*)(pb + j);
    float av[4] = {a.x, a.y, a.z, a.w};
    float bv[4] = {b.x, b.y, b.z, b.w};
    #pragma unroll
    for (int q = 0; q < 4; q++) {
      As[ldc + j + q][lr] = av[q];
      Bs[ldc + j + q][lr] = bv[q];
    }
  }
  __syncthreads();
  int tr = t >> 4, tc = t & 15;
  float acc[4][4] = {};
  #pragma unroll 16
  for (int k = 0; k < DD; k++) {
    float4 a = *(const float4*)&As[k][tr * 4];
    float4 b = *(const float4*)&Bs[k][tc * 4];
    float ar[4] = {a.x, a.y, a.z, a.w};
    float br[4] = {b.x, b.y, b.z, b.w};
    #pragma unroll
    for (int i = 0; i < 4; i++)
      #pragma unroll
      for (int j = 0; j < 4; j++)
        acc[i][j] += ar[i] * br[j];
  }
  int grow = brow + tr * 4;
  #pragma unroll
  for (int i = 0; i < 4; i++) {
    float4 o = {acc[i][0], acc[i][1], acc[i][2], acc[i][3]};
    *(float4*)(sim + (size_t)(grow + i) * NN + bcol + tc * 4) = o;
  }
}

// ---------------------------------------------------------------------------
// Kernel 3: EXACT top-15 per row via threshold selection (round-11, passing).
__global__ __launch_bounds__(256) void topk_kernel(
    const float* __restrict__ sim, int* __restrict__ src) {
  int t = threadIdx.x;
  int n = blockIdx.x;
  const float* row = sim + (size_t)n * NN;

  __shared__ __align__(16) unsigned cand[64];
  __shared__ unsigned s_thr;
  __shared__ int s_cgt, s_cnt, s_tie_cnt;
  __shared__ int s_tie[64];
  if (t == 0) { s_cnt = 0; s_tie_cnt = 0; }

  unsigned k0[16];
  #pragma unroll
  for (int c = 0; c < 4; c++) {
    float4 f = *(const float4*)(row + c * 1024 + t * 4);
    float fv[4] = {f.x, f.y, f.z, f.w};
    #pragma unroll
    for (int e = 0; e < 4; e++) {
      unsigned u = __float_as_uint(fv[e]);
      k0[c * 4 + e] = u ^ ((unsigned)(((int)u) >> 31) | 0x80000000u);  // exact
    }
  }
  unsigned s[16];
  #pragma unroll
  for (int i = 0; i < 16; i++) s[i] = k0[i];

  // bitonic sort-16 descending
  #pragma unroll
  for (int k = 2; k <= 16; k <<= 1) {
    #pragma unroll
    for (int j = k >> 1; j > 0; j >>= 1) {
      #pragma unroll
      for (int i = 0; i < 16; i++) {
        int ixj = i ^ j;
        if (ixj > i) {
          unsigned a = s[i], b = s[ixj];
          unsigned mx = (a > b) ? a : b;
          unsigned mn = (a > b) ? b : a;
          if ((i & k) == 0) { s[i] = mx; s[ixj] = mn; }
          else              { s[i] = mn; s[ixj] = mx; }
        }
      }
    }
  }

#define MERGE_ROUND(EXPR)                                                    \
  {                                                                          \
    unsigned p[16];                                                          \
    _Pragma("unroll")                                                        \
    for (int i = 0; i < 16; i++) { unsigned x = s[i]; p[i] = (unsigned)(EXPR); } \
    unsigned m[16];                                                          \
    _Pragma("unroll")                                                        \
    for (int i = 0; i < 16; i++) {                                           \
      unsigned q = p[15 - i];                                                \
      m[i] = (s[i] > q) ? s[i] : q;                                          \
    }                                                                        \
    _Pragma("unroll")                                                        \
    for (int j = 8; j > 0; j >>= 1) {                                        \
      _Pragma("unroll")                                                      \
      for (int i = 0; i < 16; i++) {                                         \
        int ixj = i ^ j;                                                     \
        if (ixj > i) {                                                       \
          unsigned a = m[i], b = m[ixj];                                     \
          m[i]   = (a > b) ? a : b;                                          \
          m[ixj] = (a > b) ? b : a;                                          \
        }                                                                    \
      }                                                                      \
    }                                                                        \
    _Pragma("unroll")                                                        \
    for (int i = 0; i < 16; i++) s[i] = m[i];                                \
  }

  MERGE_ROUND(__builtin_amdgcn_update_dpp(0, (int)x, 0xB1, 0xF, 0xF, true))  // xor1
  MERGE_ROUND(__builtin_amdgcn_update_dpp(0, (int)x, 0x4E, 0xF, 0xF, true))  // xor2
  MERGE_ROUND(__shfl_xor((int)x, 4))
  MERGE_ROUND(__shfl_xor((int)x, 8))
  MERGE_ROUND(__shfl_xor((int)x, 16))
  MERGE_ROUND(__shfl_xor((int)x, 32))
#undef MERGE_ROUND

  int wv = t >> 6, l = t & 63;
  if (l == 0) {
    #pragma unroll
    for (int i = 0; i < 16; i++) cand[wv * 16 + i] = s[i];
  }
  __syncthreads();

  if (t < 64) {
    unsigned my = cand[t];
    int r = 0, eq = 0;
    #pragma unroll
    for (int i = 0; i < 64; i += 4) {
      uint4 c4 = *(const uint4*)&cand[i];
      r  += (c4.x > my) + (c4.y > my) + (c4.z > my) + (c4.w > my);
      eq += (c4.x == my) + (c4.y == my) + (c4.z == my) + (c4.w == my);
    }
    if (r <= 14 && r + eq >= 15) { s_thr = my; s_cgt = r; }  // benign multi-write
  }
  __syncthreads();

  unsigned thr = s_thr;
  #pragma unroll
  for (int q = 0; q < 16; q++) {
    unsigned kv = k0[q];
    if (kv > thr) {
      int slot = atomicAdd(&s_cnt, 1);
      src[n * KK + slot] = ((q >> 2) << 10) + t * 4 + (q & 3);
    } else if (kv == thr) {
      int ts = atomicAdd(&s_tie_cnt, 1);
      if (ts < 64) s_tie[ts] = ((q >> 2) << 10) + t * 4 + (q & 3);
    }
  }
  __syncthreads();
  if (t == 0) {
    int cgt = s_cgt;
    int tn = s_tie_cnt; if (tn > 64) tn = 64;
    for (int slot = cgt; slot < KK; slot++) {
      int best = 1 << 30, bi = 0;
      for (int i = 0; i < tn; i++)
        if (s_tie[i] < best) { best = s_tie[i]; bi = i; }
      src[n * KK + slot] = best;
      s_tie[bi] = 1 << 30;
    }
  }
}

// ---------------------------------------------------------------------------
// Kernel 4 (fused gcn+mlp), one block per node n.
// Round-14 change: issue ALL 15 xh gather loads into registers immediately
// after s_src is visible, so HBM/L3 latency hides under the alpha+softmax
// compute (A/B test: latency-bound vs bytes-bound). bfrag load deferred to
// phase B to cap VGPR pressure during the gather window.
__global__ __launch_bounds__(256) void gcn_mlp_kernel(
    const int* __restrict__ src, const float* __restrict__ ei,
    const float* __restrict__ ej, const float* __restrict__ xi,
    const float* __restrict__ xj, const short* __restrict__ xh,
    const float* __restrict__ emb, const short* __restrict__ w1b,
    const float* __restrict__ b1, const float* __restrict__ w2,
    const float* __restrict__ b2, float* __restrict__ y) {
  int n = blockIdx.x, t = threadIdx.x;
  int w = t >> 6, l = t & 63;
  int lm = l & 15, lk = l >> 4;

  __shared__ int s_src[KK];
  __shared__ float s_ej[KK], s_xi[BB], s_alpha[KK][BB], s_emb[DD];
  __shared__ __align__(16) short out_lds[256 * 8];  // 4 KB, swizzled 16B slots
  __shared__ float part[4][32];

  if (t < KK) { int m = src[n * KK + t]; s_src[t] = m; s_ej[t] = ej[m]; }
  if (t >= 32 && t < 64) s_xi[t - 32] = xi[n * BB + (t - 32)];
  if (t >= 64 && t < 128) s_emb[t - 64] = emb[(size_t)n * DD + (t - 64)];
  __syncthreads();

  // issue all 15 gathers NOW; results consumed two barriers later
  int b = t >> 3, d0 = (t & 7) * 8;
  s16x8 g[KK];
  #pragma unroll
  for (int k = 0; k < KK; k++)
    g[k] = *(const s16x8*)(xh + ((size_t)s_src[k] * BB + b) * DD + d0);

  // alpha logits (xj gather overlaps with xh loads in flight)
  for (int idx = t; idx < KK * BB; idx += 256) {
    int k = idx >> 5, bb = idx & 31;
    float a = ei[n] + s_xi[bb] + s_ej[k] + xj[s_src[k] * BB + bb];
    a = (a > 0.f) ? a : 0.2f * a;
    s_alpha[k][bb] = a;
  }
  __syncthreads();
  if (t < BB) {
    float p[KK];
    float mx = -1e30f;
    #pragma unroll
    for (int k = 0; k < KK; k++) mx = fmaxf(mx, s_alpha[k][t]);
    float s = 0.f;
    #pragma unroll
    for (int k = 0; k < KK; k++) { p[k] = expf(s_alpha[k][t] - mx); s += p[k]; }
    float inv = 1.f / s;
    #pragma unroll
    for (int k = 0; k < KK; k++) s_alpha[k][t] = p[k] * inv;
  }
  __syncthreads();
  {
    float acc[8] = {};
    #pragma unroll
    for (int k = 0; k < KK; k++) {
      float a = s_alpha[k][b];
      #pragma unroll
      for (int j = 0; j < 8; j++) acc[j] += a * bf2f(g[k][j]);
    }
    s16x8 o;
    #pragma unroll
    for (int j = 0; j < 8; j++) o[j] = f2bf(acc[j] * s_emb[d0 + j]);
    int slot = (t & ~7) | ((t & 7) ^ ((t >> 3) & 7));
    *(s16x8*)&out_lds[slot * 8] = o;
  }
  __syncthreads();

  // B-operand fragments (w1b is L2-resident, 32 KB): wave w owns cols 64w..64w+63
  s16x8 bfrag[4][2];
  float b1v[4], w2v[4];
  #pragma unroll
  for (int j = 0; j < 4; j++) {
    int c = 64 * w + 16 * j + lm;
    #pragma unroll
    for (int s = 0; s < 2; s++)
      bfrag[j][s] = *(const s16x8*)(w1b + (size_t)c * DD + s * 32 + lk * 8);
    b1v[j] = b1[c];
    w2v[j] = w2[c];
  }
  float b2v = b2[0];

  // Phase B: A(32x64) @ w1^T. A-frag lane l, row-tile i, k-half s:
  //   row b = 16i+lm, k-bytes owned by phase-A thread t' = b*8 + (4s+lk)
  f32x4 acc2[2][4] = {};
  #pragma unroll
  for (int s = 0; s < 2; s++) {
    s16x8 afrag[2];
    #pragma unroll
    for (int i = 0; i < 2; i++) {
      int bb = 16 * i + lm;
      int jj = 4 * s + lk;
      int sl = bb * 8 + (jj ^ (bb & 7));
      afrag[i] = *(const s16x8*)&out_lds[sl * 8];
    }
    #pragma unroll
    for (int i = 0; i < 2; i++)
      #pragma unroll
      for (int j = 0; j < 4; j++)
        acc2[i][j] = __builtin_amdgcn_mfma_f32_16x16x32_bf16(
            afrag[i], bfrag[j][s], acc2[i][j], 0, 0, 0);
  }
  // epilogue: relu + w2-weighted col sum, reduce over 16 col-lanes (lm)
  float p[2][4];
  #pragma unroll
  for (int i = 0; i < 2; i++)
    #pragma unroll
    for (int r = 0; r < 4; r++) {
      float sum = 0.f;
      #pragma unroll
      for (int j = 0; j < 4; j++) {
        float h = acc2[i][j][r] + b1v[j];
        h = fmaxf(h, 0.f);
        sum += h * w2v[j];
      }
      p[i][r] = sum;
    }
  #pragma unroll
  for (int off = 1; off < 16; off <<= 1)
    #pragma unroll
    for (int i = 0; i < 2; i++)
      #pragma unroll
      for (int r = 0; r < 4; r++)
        p[i][r] += __shfl_xor(p[i][r], off);
  if (lm == 0) {
    #pragma unroll
    for (int i = 0; i < 2; i++)
      #pragma unroll
      for (int r = 0; r < 4; r++)
        part[w][16 * i + 4 * lk + r] = p[i][r];
  }
  __syncthreads();
  if (t < BB)
    y[(size_t)t * NN + n] = b2v + part[0][t] + part[1][t] + part[2][t] + part[3][t];
}

// ---------------------------------------------------------------------------
extern "C" void kernel_launch(void* const* d_in, const int* in_sizes, int n_in,
                              void* d_out, int out_size, void* d_ws, size_t ws_size,
                              hipStream_t stream) {
  const float* x     = (const float*)d_in[0];
  const float* emb   = (const float*)d_in[1];
  const float* lin_w = (const float*)d_in[2];
  const float* att   = (const float*)d_in[3];
  const float* w1    = (const float*)d_in[4];
  const float* b1    = (const float*)d_in[5];
  const float* w2    = (const float*)d_in[6];
  const float* b2    = (const float*)d_in[7];
  float* y = (float*)d_out;

  char* ws = (char*)d_ws;
  // workspace layout (256B aligned), peak ~86.3 MB
  float* ne     = (float*)(ws + 0);          // N*D f32      = 1,048,576 B
  float* ei     = (float*)(ws + 1048576);    // N f32        =    16,384 B
  float* ej     = (float*)(ws + 1064960);    // N f32        =    16,384 B
  float* xi     = (float*)(ws + 1081344);    // N*B f32      =   524,288 B
  float* xj     = (float*)(ws + 1605632);    // N*B f32      =   524,288 B
  int*   srcbuf = (int*)  (ws + 2129920);    // N*K i32      =   245,760 B
  short* w1b    = (short*)(ws + 2375680);    // H*D bf16     =    32,768 B
  short* xh     = (short*)(ws + 2408448);    // N*B*D bf16   = 16,777,216 B
  float* simbuf = (float*)(ws + 19185664);   // N*N f32      = 67,108,864 B

  front_kernel<<<NN * BB / 4 + 64 + NN / 4, 256, 0, stream>>>(
      x, lin_w, att, xh, xi, xj, w1, w1b, emb, ne, ei, ej);

  dim3 g(64, 64);
  sim_kernel<<<g, 256, 0, stream>>>(ne, simbuf);
  topk_kernel<<<NN, 256, 0, stream>>>(simbuf, srcbuf);

  gcn_mlp_kernel<<<NN, 256, 0, stream>>>(srcbuf, ei, ej, xi, xj, xh, emb,
                                         w1b, b1, w2, b2, y);
}